// Round 5
// baseline (565.137 us; speedup 1.0000x reference)
//
#include <hip/hip_runtime.h>
#include <hip/hip_bf16.h>
#include <math.h>

// Problem constants (fixed by setup_inputs())
#define F_DIM 256
#define D_DIM 128
#define O_DIM 64
#define NS0   100000
#define ND0   25000
#define E0_N  500000
#define NS1   25000
#define ND1   5000
#define E1_N  100000

#define NBE0  1954   // ceil(E0_N/256)
#define NBE1  391    // ceil(E1_N/256)
#define NB_CSR (2 * NBE0 + 2 * NBE1)
#define NB_WPREP 576

typedef __attribute__((ext_vector_type(8))) short s8v;   // 8 bf16 (4 VGPRs)
typedef __attribute__((ext_vector_type(4))) float f4v;   // 4 fp32 acc

struct CPtr4 { const int *p0, *p1, *p2, *p3; };
struct MPtr4 { int *p0, *p1, *p2, *p3; };

__device__ __forceinline__ float2 unpack2(uint u) {
    union { uint i; float f; } a, b;
    a.i = (u & 0xffffu) << 16; b.i = u & 0xffff0000u;
    return make_float2(a.f, b.f);
}
__device__ __forceinline__ ushort f2bf(float f) {
    __hip_bfloat16 h = __float2bfloat16(f);
    return *(ushort*)&h;
}
__device__ __forceinline__ float u2f(uint u) {
    union { uint i; float f; } v; v.i = u; return v.f;
}
__device__ __forceinline__ uint f2u(float f) {
    union { uint i; float f; } v; v.f = f; return v.i;
}

// ---------------------------------------------------------------------------
// Layer-0 GEMM, dual-mode A-sharing, WITH FUSED node_proj (L1).
// After the K-loop the block holds z rows [row0,row0+64) x 128 cols x 2 modes.
// The bf16 z values are stashed in LDS (aliasing dead As/Bs) and the
// node_proj inner loop (identical slices/reduction tree) writes the packed
// attn tables directly -- eliminating the node_proj L1 kernel + 51MB re-read.
// ---------------------------------------------------------------------------
__global__ __launch_bounds__(256) void gemm_l0(
    const float* __restrict__ A,          // feat [M][256] fp32
    const ushort* __restrict__ Btb,       // Wtin [2][128][256] bf16
    const float* __restrict__ biasb,      // b_in [2][128]
    const float* __restrict__ Web,        // ea1 [2][256][2]
    const float* __restrict__ Wib,        // ia1 [2][256][1]
    ushort* __restrict__ Coutb, size_t coutstr,
    float4* __restrict__ ecor, float4* __restrict__ esim,
    float* __restrict__ pdb, float* __restrict__ qdb,
    int M, int n_dst)
{
    constexpr int PA = 40;
    // pool: K-loop uses As(5120B)+Bs(20480B)=25600B; epilogue reuses it as
    // zs[2][64][128] ushort = 32768B.
    __shared__ __align__(16) char pool[32768];
    ushort* As = (ushort*)pool;                       // [64*PA]
    ushort* Bsb = (ushort*)(pool + 64 * PA * 2);      // [2][128*PA]

    const int tid = threadIdx.x;
    const int row0 = blockIdx.x * 64;
    const int wave = tid >> 6, lane = tid & 63;
    const int l15 = lane & 15, l4 = lane >> 4;
    const int wm0 = (wave >> 1) * 32;   // 0 or 32
    const int wn0 = (wave & 1) * 64;    // 0 or 64

    f4v acc[2][2][4];
    #pragma unroll
    for (int m2 = 0; m2 < 2; ++m2)
        #pragma unroll
        for (int i = 0; i < 2; ++i)
            #pragma unroll
            for (int j = 0; j < 4; ++j)
                acc[m2][i][j] = (f4v)(0.0f);

    for (int kc = 0; kc < F_DIM; kc += 32) {
        __syncthreads();
        // A chunk: 64 rows x 32 fp32 -> bf16
        {
            int r = tid >> 2, g = (tid & 3) * 8;
            int gr = row0 + r;
            float4 v0 = make_float4(0.f, 0.f, 0.f, 0.f);
            float4 v1 = make_float4(0.f, 0.f, 0.f, 0.f);
            if (gr < M) {
                v0 = *(const float4*)(A + (size_t)gr * F_DIM + kc + g);
                v1 = *(const float4*)(A + (size_t)gr * F_DIM + kc + g + 4);
            }
            ushort4 o0, o1;
            o0.x = f2bf(v0.x); o0.y = f2bf(v0.y); o0.z = f2bf(v0.z); o0.w = f2bf(v0.w);
            o1.x = f2bf(v1.x); o1.y = f2bf(v1.y); o1.z = f2bf(v1.z); o1.w = f2bf(v1.w);
            *(ushort4*)(&As[r * PA + g]) = o0;
            *(ushort4*)(&As[r * PA + g + 4]) = o1;
        }
        // B chunks: both modes, 128 rows x 32 bf16 each
        #pragma unroll
        for (int m2 = 0; m2 < 2; ++m2)
            #pragma unroll
            for (int it = 0; it < 2; ++it) {
                int f = tid + it * 256;
                int r = f >> 2, g = (f & 3) * 8;
                *(float4*)(&Bsb[m2 * 128 * PA + r * PA + g]) =
                    *(const float4*)(Btb + m2 * (D_DIM * F_DIM) + (size_t)r * F_DIM + kc + g);
            }
        __syncthreads();

        s8v af[2];
        #pragma unroll
        for (int i = 0; i < 2; ++i)
            af[i] = *(const s8v*)(&As[(wm0 + i * 16 + l15) * PA + l4 * 8]);
        #pragma unroll
        for (int m2 = 0; m2 < 2; ++m2) {
            s8v bfr[4];
            #pragma unroll
            for (int j = 0; j < 4; ++j)
                bfr[j] = *(const s8v*)(&Bsb[m2 * 128 * PA + (wn0 + j * 16 + l15) * PA + l4 * 8]);
            #pragma unroll
            for (int i = 0; i < 2; ++i)
                #pragma unroll
                for (int j = 0; j < 4; ++j)
                    acc[m2][i][j] = __builtin_amdgcn_mfma_f32_16x16x32_bf16(
                        af[i], bfr[j], acc[m2][i][j], 0, 0, 0);
        }
    }

    // ---- epilogue: global z store + LDS z stash ----
    __syncthreads();                       // As/Bs now dead
    ushort* zs = (ushort*)pool;            // [2][64][128]
    #pragma unroll
    for (int m2 = 0; m2 < 2; ++m2)
        #pragma unroll
        for (int i = 0; i < 2; ++i)
            #pragma unroll
            for (int ii = 0; ii < 4; ++ii) {
                int r = wm0 + i * 16 + l4 * 4 + ii;
                int row = row0 + r;
                if (row < M) {
                    #pragma unroll
                    for (int j = 0; j < 4; ++j) {
                        int col = wn0 + j * 16 + l15;
                        ushort u = f2bf(acc[m2][i][j][ii] + biasb[m2 * D_DIM + col]);
                        Coutb[m2 * coutstr + (size_t)row * D_DIM + col] = u;
                        zs[m2 * 8192 + r * 128 + col] = u;
                    }
                }
            }
    __syncthreads();

    // ---- fused node_proj: threads 0-127 mode0, 128-255 mode1 ----
    {
        const int m2 = tid >> 7;
        const int sub = tid & 7;
        const int gg = (tid >> 3) & 15;
        const float* We = Web + m2 * 512;
        const float* Wi = Wib + m2 * 256;

        float wr[6][16];
        #pragma unroll
        for (int kk = 0; kk < 16; ++kk) {
            int k = sub * 16 + kk;
            wr[0][kk] = We[k * 2 + 0];
            wr[1][kk] = We[k * 2 + 1];
            wr[2][kk] = Wi[k];
            wr[3][kk] = We[(D_DIM + k) * 2 + 0];
            wr[4][kk] = We[(D_DIM + k) * 2 + 1];
            wr[5][kk] = Wi[D_DIM + k];
        }

        #pragma unroll
        for (int it = 0; it < 4; ++it) {
            int r = it * 16 + gg;
            int node = row0 + r;
            if (node >= M) continue;
            const ushort* zp = zs + m2 * 8192 + r * 128 + sub * 16;
            uint4 ra = *(const uint4*)zp;
            uint4 rb = *(const uint4*)(zp + 8);
            uint rr[8] = {ra.x, ra.y, ra.z, ra.w, rb.x, rb.y, rb.z, rb.w};
            float p[6] = {0.f, 0.f, 0.f, 0.f, 0.f, 0.f};
            #pragma unroll
            for (int e = 0; e < 8; ++e) {
                float2 f2 = unpack2(rr[e]);
                #pragma unroll
                for (int c = 0; c < 6; ++c)
                    p[c] += f2.x * wr[c][2 * e] + f2.y * wr[c][2 * e + 1];
            }
            #pragma unroll
            for (int off = 4; off > 0; off >>= 1)
                #pragma unroll
                for (int c = 0; c < 6; ++c)
                    p[c] += __shfl_down(p[c], off);

            if (sub == 0) {
                if (m2 == 0) {
                    *(float2*)&ecor[node] = make_float2(p[0], p[1]);
                    ((float*)&esim[node])[2] = p[2];
                } else {
                    *(float2*)&esim[node] = make_float2(p[0], p[1]);
                    ((float*)&ecor[node])[2] = p[2];
                }
                if (node < n_dst) {
                    *(float2*)(pdb + (size_t)m2 * ND0 * 2 + 2 * (size_t)node) =
                        make_float2(p[3], p[4]);
                    qdb[(size_t)m2 * ND0 + node] = p[5];
                }
            }
        }
    }
}

// ---------------------------------------------------------------------------
// MFMA bf16 GEMM, mode-fused (blockIdx.y = m), bf16 A.
// EPI 1: +bias -> f32
// EPI 2 (agg-fused): out = partial + 0.5*relu(acc + c[row]*bias[col]) -> bf16
// ---------------------------------------------------------------------------
template<int NW, int KD, int EPI>
__global__ __launch_bounds__(256) void mfma_gemm(
    const ushort* __restrict__ Ab, size_t astr,
    const ushort* __restrict__ Btb, size_t btstr,
    const float* __restrict__ biasb, size_t bstr,
    const float* __restrict__ cvecb, size_t cvstr,
    const float* __restrict__ partialb, size_t pstr,
    void* __restrict__ Coutb, size_t coutstr, int M)
{
    const int m = blockIdx.y;
    const ushort* A = Ab + m * astr;
    const ushort* Bt = Btb + m * btstr;
    const float* bias = biasb + m * bstr;
    const float* cvec = (EPI == 2) ? cvecb + m * cvstr : nullptr;
    const float* partial = (EPI == 2) ? partialb + m * pstr : nullptr;
    char* Cout = (char*)Coutb + m * coutstr * (EPI == 1 ? 4 : 2);

    constexpr int PA = 40;
    constexpr int WAVES_M = (NW == 128) ? 2 : 4;
    constexpr int WM = 128 / WAVES_M;
    constexpr int TM = WM / 16;
    constexpr int TN = 4;
    __shared__ ushort As[128 * PA];
    __shared__ ushort Bs[NW * PA];

    const int tid  = threadIdx.x;
    const int row0 = blockIdx.x * 128;
    const int wave = tid >> 6, lane = tid & 63;
    const int l15 = lane & 15, l4 = lane >> 4;
    int wm0, wn0;
    if (NW == 128) { wm0 = (wave >> 1) * 64; wn0 = (wave & 1) * 64; }
    else           { wm0 = wave * WM;        wn0 = 0; }

    f4v acc[TM][TN];
    #pragma unroll
    for (int i = 0; i < TM; ++i)
        #pragma unroll
        for (int j = 0; j < TN; ++j)
            acc[i][j] = (f4v)(0.0f);

    for (int kc = 0; kc < KD; kc += 32) {
        __syncthreads();
        #pragma unroll
        for (int it = 0; it < 2; ++it) {
            int f = tid + it * 256;
            int r = f >> 2, g = (f & 3) * 8;
            int gr = row0 + r;
            float4 v = make_float4(0.f, 0.f, 0.f, 0.f);
            if (gr < M) v = *(const float4*)(A + (size_t)gr * KD + kc + g);
            *(float4*)(&As[r * PA + g]) = v;
        }
        #pragma unroll
        for (int it = 0; it < NW * 32 / (256 * 8); ++it) {
            int f = tid + it * 256;
            int r = f >> 2, g = (f & 3) * 8;
            *(float4*)(&Bs[r * PA + g]) = *(const float4*)(Bt + (size_t)r * KD + kc + g);
        }
        __syncthreads();

        s8v af[TM], bfr[TN];
        #pragma unroll
        for (int i = 0; i < TM; ++i)
            af[i] = *(const s8v*)(&As[(wm0 + i * 16 + l15) * PA + l4 * 8]);
        #pragma unroll
        for (int j = 0; j < TN; ++j)
            bfr[j] = *(const s8v*)(&Bs[(wn0 + j * 16 + l15) * PA + l4 * 8]);
        #pragma unroll
        for (int i = 0; i < TM; ++i)
            #pragma unroll
            for (int j = 0; j < TN; ++j)
                acc[i][j] = __builtin_amdgcn_mfma_f32_16x16x32_bf16(
                    af[i], bfr[j], acc[i][j], 0, 0, 0);
    }

    #pragma unroll
    for (int i = 0; i < TM; ++i) {
        #pragma unroll
        for (int ii = 0; ii < 4; ++ii) {
            int row = row0 + wm0 + i * 16 + l4 * 4 + ii;
            if (row < M) {
                #pragma unroll
                for (int j = 0; j < TN; ++j) {
                    int col = wn0 + j * 16 + l15;
                    float a = acc[i][j][ii];
                    if (EPI == 1) {
                        ((float*)Cout)[(size_t)row * NW + col] = a + bias[col];
                    } else {
                        float val = a + cvec[row] * bias[col];
                        float o = partial[(size_t)row * NW + col] + 0.5f * fmaxf(val, 0.f);
                        ((ushort*)Cout)[(size_t)row * NW + col] = f2bf(o);
                    }
                }
            }
        }
    }
}

// ---------------------------------------------------------------------------
// CSR histogram (4 edge lists batched) + weight transpose merged in one grid.
// ---------------------------------------------------------------------------
__global__ void histo4_prep(CPtr4 ed, MPtr4 cnt,
    const float* __restrict__ Win, const float* __restrict__ W1,
    const float* __restrict__ W2,  const float* __restrict__ Wout,
    ushort* __restrict__ Wtin, ushort* __restrict__ Wt1,
    ushort* __restrict__ Wt2,  ushort* __restrict__ Wtout)
{
    int b = blockIdx.x, t = threadIdx.x;
    if (b >= NB_CSR) {
        int i = (b - NB_CSR) * 256 + t;
        if (i < 65536) {
            int m = i >> 15, r = i & 32767, k = r >> 7, n = r & 127;
            Wtin[m * 32768 + n * 256 + k] = f2bf(Win[m * 32768 + k * 128 + n]);
        } else if (i < 98304) {
            int i2 = i - 65536;
            int m = i2 >> 14, r = i2 & 16383, k = r >> 7, n = r & 127;
            Wt1[m * 16384 + n * 128 + k] = f2bf(W1[m * 16384 + k * 128 + n]);
        } else if (i < 131072) {
            int i2 = i - 98304;
            int m = i2 >> 14, r = i2 & 16383, k = r >> 7, n = r & 127;
            Wt2[m * 16384 + n * 128 + k] = f2bf(W2[m * 16384 + k * 128 + n]);
        } else if (i < 147456) {
            int i2 = i - 131072;
            int m = i2 >> 13, r = i2 & 8191, k = r >> 6, n = r & 63;
            Wtout[m * 8192 + n * 128 + k] = f2bf(Wout[m * 8192 + k * 64 + n]);
        }
        return;
    }
    const int* edp; int* cp; int e, E;
    if (b < NBE0)          { edp = ed.p0; cp = cnt.p0; e = b * 256 + t;              E = E0_N; }
    else if (b < 2 * NBE0) { edp = ed.p1; cp = cnt.p1; e = (b - NBE0) * 256 + t;     E = E0_N; }
    else if (b < 2 * NBE0 + NBE1)
                           { edp = ed.p2; cp = cnt.p2; e = (b - 2 * NBE0) * 256 + t; E = E1_N; }
    else                   { edp = ed.p3; cp = cnt.p3; e = (b - 2 * NBE0 - NBE1) * 256 + t; E = E1_N; }
    if (e < E) atomicAdd(&cp[edp[e]], 1);
}

__global__ __launch_bounds__(1024) void exscan4(MPtr4 cnt, MPtr4 row, MPtr4 head)
{
    __shared__ int part[1024];
    const int b = blockIdx.x, t = threadIdx.x;
    int* cp; int* rp; int* hp; int n;
    if (b == 0)      { cp = cnt.p0; rp = row.p0; hp = head.p0; n = ND0; }
    else if (b == 1) { cp = cnt.p1; rp = row.p1; hp = head.p1; n = ND0; }
    else if (b == 2) { cp = cnt.p2; rp = row.p2; hp = head.p2; n = ND1; }
    else             { cp = cnt.p3; rp = row.p3; hp = head.p3; n = ND1; }

    const int chunk = (n + 1023) >> 10;
    const int start = t * chunk;
    int s = 0;
    for (int i = 0; i < chunk; ++i) {
        int idx = start + i;
        if (idx < n) s += cp[idx];
    }
    part[t] = s;
    __syncthreads();
    for (int off = 1; off < 1024; off <<= 1) {
        int v = (t >= off) ? part[t - off] : 0;
        __syncthreads();
        part[t] += v;
        __syncthreads();
    }
    int run = (t == 0) ? 0 : part[t - 1];
    for (int i = 0; i < chunk; ++i) {
        int idx = start + i;
        if (idx < n) { rp[idx] = run; hp[idx] = run; run += cp[idx]; }
    }
    if (t == 1023) rp[n] = part[1023];
}

__global__ void build4(CPtr4 es, CPtr4 ed, MPtr4 head, MPtr4 src)
{
    int b = blockIdx.x, t = threadIdx.x;
    const int *esp, *edp; int *hp, *sp; int e, E;
    if (b < NBE0)          { esp = es.p0; edp = ed.p0; hp = head.p0; sp = src.p0; e = b * 256 + t;              E = E0_N; }
    else if (b < 2 * NBE0) { esp = es.p1; edp = ed.p1; hp = head.p1; sp = src.p1; e = (b - NBE0) * 256 + t;     E = E0_N; }
    else if (b < 2 * NBE0 + NBE1)
                           { esp = es.p2; edp = ed.p2; hp = head.p2; sp = src.p2; e = (b - 2 * NBE0) * 256 + t; E = E1_N; }
    else                   { esp = es.p3; edp = ed.p3; hp = head.p3; sp = src.p3; e = (b - 2 * NBE0 - NBE1) * 256 + t; E = E1_N; }
    if (e >= E) return;
    int p = atomicAdd(&hp[edp[e]], 1);
    sp[p] = esp[e];
}

// ---------------------------------------------------------------------------
// Per-node projections (LAYER 2 ONLY now; L1 fused into gemm_l0).
//   ecor[s] = { p0_m0, p1_m0, q_m1, - }   (cor list: e-ch mode0, i-ch mode1)
//   esim[s] = { p0_m1, p1_m1, q_m0, - }   (sim list: e-ch mode1, i-ch mode0)
// ---------------------------------------------------------------------------
#define NP_NPB 128
__global__ __launch_bounds__(256) void node_proj(
    const ushort* __restrict__ zb, size_t zstr,
    const float* __restrict__ Web, const float* __restrict__ Wib,
    float4* __restrict__ ecor, float4* __restrict__ esim,
    float* __restrict__ pdb, float* __restrict__ qdb,
    int n_src, int n_dst)
{
    const int m = blockIdx.y;
    const ushort* z = zb + m * zstr;
    const float* We = Web + m * 512;
    const float* Wi = Wib + m * 256;

    __shared__ float w[6][D_DIM];
    for (int k = threadIdx.x; k < D_DIM; k += 256) {
        w[0][k] = We[k * 2 + 0];
        w[1][k] = We[k * 2 + 1];
        w[2][k] = Wi[k];
        w[3][k] = We[(D_DIM + k) * 2 + 0];
        w[4][k] = We[(D_DIM + k) * 2 + 1];
        w[5][k] = Wi[D_DIM + k];
    }
    __syncthreads();

    const int sub = threadIdx.x & 7;
    const int g   = threadIdx.x >> 3;

    float wr[6][16];
    #pragma unroll
    for (int c = 0; c < 6; ++c)
        #pragma unroll
        for (int q = 0; q < 4; ++q) {
            float4 f = *(const float4*)(&w[c][sub * 16 + q * 4]);
            wr[c][q * 4 + 0] = f.x; wr[c][q * 4 + 1] = f.y;
            wr[c][q * 4 + 2] = f.z; wr[c][q * 4 + 3] = f.w;
        }

    #pragma unroll
    for (int it = 0; it < 4; ++it) {
        int node = blockIdx.x * NP_NPB + it * 32 + g;
        if (node >= n_src) continue;
        const ushort* zp = z + (size_t)node * D_DIM + sub * 16;
        uint4 ra = *(const uint4*)zp;
        uint4 rb = *(const uint4*)(zp + 8);
        uint rr[8] = {ra.x, ra.y, ra.z, ra.w, rb.x, rb.y, rb.z, rb.w};
        float p[6] = {0.f, 0.f, 0.f, 0.f, 0.f, 0.f};
        #pragma unroll
        for (int e = 0; e < 8; ++e) {
            float2 f2 = unpack2(rr[e]);
            #pragma unroll
            for (int c = 0; c < 6; ++c)
                p[c] += f2.x * wr[c][2 * e] + f2.y * wr[c][2 * e + 1];
        }
        #pragma unroll
        for (int off = 4; off > 0; off >>= 1)
            #pragma unroll
            for (int c = 0; c < 6; ++c)
                p[c] += __shfl_down(p[c], off);

        if (sub == 0) {
            if (m == 0) {
                *(float2*)&ecor[node] = make_float2(p[0], p[1]);
                ((float*)&esim[node])[2] = p[2];
            } else {
                *(float2*)&esim[node] = make_float2(p[0], p[1]);
                ((float*)&ecor[node])[2] = p[2];
            }
            if (node < n_dst) {
                *(float2*)(pdb + (size_t)m * ND0 * 2 + 2 * (size_t)node) = make_float2(p[3], p[4]);
                qdb[(size_t)m * ND0 + node] = p[5];
            }
        }
    }
}

// ---------------------------------------------------------------------------
// FUSED edge attention + gather, per-(dst, mode) wave (blockIdx.y = mode).
// REVERTED to the R1-measured-best structure (82.9us @ 270MB FETCH):
// sequential e-loop then i-loop, chunked, single LDS scratch, unpredicated
// full batches + predicated tail. Only change vs R1: packed ecor/esim tables.
// ---------------------------------------------------------------------------
__global__ __launch_bounds__(256) void edge_gather4(
    const ushort* __restrict__ zb, size_t zstr,
    const float4* __restrict__ ecor, const float4* __restrict__ esim,
    const float* __restrict__ pdb, const float* __restrict__ qdb,
    const int* __restrict__ row_c, const int* __restrict__ src_c,
    const int* __restrict__ row_s, const int* __restrict__ src_s,
    ushort* __restrict__ h0base, float* __restrict__ partialb,
    float* __restrict__ cvecb, int n_dst)
{
    __shared__ uint2 sc[4][64];   // per-wave (weight, src) scratch

    const int m = blockIdx.y;
    const int wv = threadIdx.x >> 6;
    const int d = blockIdx.x * 4 + wv;
    const int lane = threadIdx.x & 63;
    if (d >= n_dst) return;

    const ushort* z = zb + (size_t)m * zstr;
    const ushort* zlane = z + lane * 2;

    const int* erow = m ? row_s : row_c;
    const int* esrc = m ? src_s : src_c;
    const int* irow = m ? row_c : row_s;
    const int* isrc = m ? src_c : src_s;
    const float4* etab = m ? esim : ecor;   // .xy = e-logits for mode m
    const float4* itab = m ? ecor : esim;   // .z  = i-logit  for mode m

    const float pd0 = pdb[(size_t)m * ND0 * 2 + 2 * d];
    const float pd1 = pdb[(size_t)m * ND0 * 2 + 2 * d + 1];
    const float qdd = qdb[(size_t)m * ND0 + d];

    float h0x = 0.f, h0y = 0.f, szx = 0.f, szy = 0.f;
    float ihx = 0.f, ihy = 0.f;
    float se0 = 0.f;

    // ---- e-channel loop
    const int b0 = erow[d], b1 = erow[d + 1];
    for (int base = b0; base < b1; base += 64) {
        const int cnt = min(64, b1 - base);
        if (lane < cnt) {
            int s = esrc[base + lane];
            float2 t = *(const float2*)&etab[s];
            float l0 = t.x + pd0, l1 = t.y + pd1;
            float mx = fmaxf(l0, l1);
            float x0 = __expf(l0 - mx), x1 = __expf(l1 - mx);
            float e0 = x0 / (x0 + x1);
            sc[wv][lane] = make_uint2(f2u(e0), (uint)s);
            se0 += e0;
        }
        asm volatile("s_waitcnt lgkmcnt(0)" ::: "memory");
        const int kf = cnt & ~7;
        int k = 0;
        for (; k < kf; k += 8) {
            uint2 ew[8]; uint rr[8];
            #pragma unroll
            for (int t = 0; t < 8; ++t) ew[t] = sc[wv][k + t];
            #pragma unroll
            for (int t = 0; t < 8; ++t) rr[t] = *(const uint*)(zlane + (size_t)ew[t].y * D_DIM);
            #pragma unroll
            for (int t = 0; t < 8; ++t) {
                float w0 = u2f(ew[t].x);
                float2 v = unpack2(rr[t]);
                szx += v.x; szy += v.y;
                h0x += w0 * v.x; h0y += w0 * v.y;
            }
        }
        if (k < cnt) {   // predicated batch of 8
            uint2 ew[8]; uint rr[8];
            #pragma unroll
            for (int t = 0; t < 8; ++t) ew[t] = sc[wv][(k + t) & 63];
            #pragma unroll
            for (int t = 0; t < 8; ++t) {
                uint s = (k + t < cnt) ? ew[t].y : 0u;
                rr[t] = *(const uint*)(zlane + (size_t)s * D_DIM);
            }
            #pragma unroll
            for (int t = 0; t < 8; ++t) {
                float sel = (k + t < cnt) ? 1.0f : 0.0f;
                float w0 = u2f(ew[t].x) * sel;
                float2 v = unpack2(rr[t]);
                szx += v.x * sel; szy += v.y * sel;
                h0x += w0 * v.x; h0y += w0 * v.y;
            }
        }
    }

    // cvec = (sum e0) / deg
    #pragma unroll
    for (int off = 32; off > 0; off >>= 1)
        se0 += __shfl_down(se0, off);
    if (lane == 0)
        cvecb[(size_t)m * ND0 + d] = se0 / fmaxf((float)(b1 - b0), 1.0f);

    // ---- i-channel loop
    const int c0 = irow[d], c1 = irow[d + 1];
    for (int base = c0; base < c1; base += 64) {
        const int cnt = min(64, c1 - base);
        if (lane < cnt) {
            int s = isrc[base + lane];
            float ti = ((const float*)&itab[s])[2];
            float sg = 1.0f / (1.0f + __expf(-(ti + qdd)));
            sc[wv][lane] = make_uint2(f2u(sg), (uint)s);
        }
        asm volatile("s_waitcnt lgkmcnt(0)" ::: "memory");
        const int kf = cnt & ~7;
        int k = 0;
        for (; k < kf; k += 8) {
            uint2 ew[8]; uint rr[8];
            #pragma unroll
            for (int t = 0; t < 8; ++t) ew[t] = sc[wv][k + t];
            #pragma unroll
            for (int t = 0; t < 8; ++t) rr[t] = *(const uint*)(zlane + (size_t)ew[t].y * D_DIM);
            #pragma unroll
            for (int t = 0; t < 8; ++t) {
                float g = u2f(ew[t].x);
                float2 v = unpack2(rr[t]);
                ihx += g * v.x; ihy += g * v.y;
            }
        }
        if (k < cnt) {
            uint2 ew[8]; uint rr[8];
            #pragma unroll
            for (int t = 0; t < 8; ++t) ew[t] = sc[wv][(k + t) & 63];
            #pragma unroll
            for (int t = 0; t < 8; ++t) {
                uint s = (k + t < cnt) ? ew[t].y : 0u;
                rr[t] = *(const uint*)(zlane + (size_t)s * D_DIM);
            }
            #pragma unroll
            for (int t = 0; t < 8; ++t) {
                float sel = (k + t < cnt) ? 1.0f : 0.0f;
                float g = u2f(ew[t].x) * sel;
                float2 v = unpack2(rr[t]);
                ihx += g * v.x; ihy += g * v.y;
            }
        }
    }

    // ---- epilogue
    const int nE = b1 - b0;
    float ehx = szx - h0x, ehy = szy - h0y;   // e1 = 1 - e0
    float inv = 1.0f / fmaxf((float)nE, 1.0f);
    uint hp = (uint)f2bf(h0x * inv) | ((uint)f2bf(h0y * inv) << 16);
    const size_t MSTR = (size_t)ND0 * D_DIM;
    *(uint*)(h0base + (size_t)m * MSTR + (size_t)d * D_DIM + lane * 2) = hp;

    float2 zd = unpack2(*(const uint*)(zlane + (size_t)d * D_DIM));
    float px = 0.5f * (fmaxf(ehx * ihx, 0.f) + zd.x);
    float py = 0.5f * (fmaxf(ehy * ihy, 0.f) + zd.y);
    *(float2*)(partialb + (size_t)m * MSTR + (size_t)d * D_DIM + lane * 2) =
        make_float2(px, py);
}

// ---------------------------------------------------------------------------
extern "C" void kernel_launch(void* const* d_in, const int* in_sizes, int n_in,
                              void* d_out, int out_size, void* d_ws, size_t ws_size,
                              hipStream_t stream)
{
    const float* feat = (const float*)d_in[0];
    const int* src0_cor = (const int*)d_in[1];
    const int* dst0_cor = (const int*)d_in[2];
    const int* src0_sim = (const int*)d_in[3];
    const int* dst0_sim = (const int*)d_in[4];
    const int* src1_cor = (const int*)d_in[5];
    const int* dst1_cor = (const int*)d_in[6];
    const int* src1_sim = (const int*)d_in[7];
    const int* dst1_sim = (const int*)d_in[8];
    const float* Win  = (const float*)d_in[11];
    const float* b_in = (const float*)d_in[12];
    const float* ea1  = (const float*)d_in[14];
    const float* ia1  = (const float*)d_in[15];
    const float* W1   = (const float*)d_in[16];
    const float* b1   = (const float*)d_in[17];
    const float* ea2  = (const float*)d_in[19];
    const float* ia2  = (const float*)d_in[20];
    const float* W2   = (const float*)d_in[21];
    const float* b2   = (const float*)d_in[22];
    const float* Wout = (const float*)d_in[23];
    const float* bout = (const float*)d_in[24];
    (void)in_sizes; (void)n_in; (void)out_size; (void)ws_size;

    // ---- workspace layout ----
    char* wsb = (char*)d_ws;
    size_t off = 0;
    auto alloc_f  = [&](size_t n) { float*  p = (float*) (wsb + off); off += n * 4; return p; };
    auto alloc_f4 = [&](size_t n) { float4* p = (float4*)(wsb + off); off += n * 16; return p; };
    auto alloc_i  = [&](size_t n) { int*    p = (int*)   (wsb + off); off += n * 4; return p; };
    auto alloc_h  = [&](size_t n) { ushort* p = (ushort*)(wsb + off); off += ((n * 2 + 15) & ~15ull); return p; };

    ushort* z0b   = alloc_h((size_t)2 * NS0 * D_DIM);
    ushort* z1b   = alloc_h((size_t)2 * NS1 * D_DIM);
    ushort* z2b   = alloc_h((size_t)2 * ND1 * D_DIM);
    ushort* h0b   = alloc_h((size_t)2 * ND0 * D_DIM);
    ushort* Wtin  = alloc_h((size_t)2 * D_DIM * F_DIM);
    ushort* Wt1   = alloc_h((size_t)2 * D_DIM * D_DIM);
    ushort* Wt2   = alloc_h((size_t)2 * D_DIM * D_DIM);
    ushort* Wtout = alloc_h((size_t)2 * O_DIM * D_DIM);

    float4* ecor   = alloc_f4((size_t)NS0);
    float4* esim   = alloc_f4((size_t)NS0);
    float* pd      = alloc_f((size_t)2 * ND0 * 2);
    float* qd      = alloc_f((size_t)2 * ND0);
    float* cvec    = alloc_f((size_t)2 * ND0);
    float* partial = alloc_f((size_t)2 * ND0 * D_DIM);

    int* src_c0 = alloc_i(E0_N); int* row_c0 = alloc_i(ND0 + 1);
    int* src_s0 = alloc_i(E0_N); int* row_s0 = alloc_i(ND0 + 1);
    int* src_c1 = alloc_i(E1_N); int* row_c1 = alloc_i(ND1 + 1);
    int* src_s1 = alloc_i(E1_N); int* row_s1 = alloc_i(ND1 + 1);
    int* cnt_all  = alloc_i(2 * ND0 + 2 * ND1);
    int* head_all = alloc_i(2 * ND0 + 2 * ND1);

    int* cnt_c0 = cnt_all;            int* head_c0 = head_all;
    int* cnt_s0 = cnt_all + ND0;      int* head_s0 = head_all + ND0;
    int* cnt_c1 = cnt_all + 2 * ND0;  int* head_c1 = head_all + 2 * ND0;
    int* cnt_s1 = cnt_c1 + ND1;       int* head_s1 = head_c1 + ND1;

    // ---- batched CSR build + weight prep ----
    hipMemsetAsync(cnt_all, 0, (size_t)(2 * ND0 + 2 * ND1) * 4, stream);
    {
        CPtr4 edp  = {dst0_cor, dst0_sim, dst1_cor, dst1_sim};
        CPtr4 esp  = {src0_cor, src0_sim, src1_cor, src1_sim};
        MPtr4 cntp = {cnt_c0, cnt_s0, cnt_c1, cnt_s1};
        MPtr4 rowp = {row_c0, row_s0, row_c1, row_s1};
        MPtr4 hdp  = {head_c0, head_s0, head_c1, head_s1};
        MPtr4 srcp = {src_c0, src_s0, src_c1, src_s1};
        histo4_prep<<<NB_CSR + NB_WPREP, 256, 0, stream>>>(
            edp, cntp, Win, W1, W2, Wout, Wtin, Wt1, Wt2, Wtout);
        exscan4<<<4, 1024, 0, stream>>>(cntp, rowp, hdp);
        build4<<<NB_CSR, 256, 0, stream>>>(esp, edp, hdp, srcp);
    }

    // ======== both modes fused ========
    const size_t Z0S = (size_t)NS0 * D_DIM, Z1S = (size_t)NS1 * D_DIM;
    const size_t Z2S = (size_t)ND1 * D_DIM, H0S = (size_t)ND0 * D_DIM;

    // --- Layer 0: z0[m] = feat @ Win[m] + b_in[m], node_proj L1 fused in epilogue
    gemm_l0<<<(NS0 + 63) / 64, 256, 0, stream>>>(
        feat, Wtin, b_in, ea1, ia1, z0b, Z0S,
        ecor, esim, pd, qd, NS0, ND0);

    // --- Layer 1
    edge_gather4<<<dim3((ND0 + 3) / 4, 2), 256, 0, stream>>>(
        z0b, Z0S, ecor, esim, pd, qd, row_c0, src_c0, row_s0, src_s0,
        h0b, partial, cvec, ND0);
    mfma_gemm<128, 128, 2><<<dim3((ND0 + 127) / 128, 2), 256, 0, stream>>>(
        h0b, H0S, Wt1, (size_t)D_DIM * D_DIM, b1, D_DIM,
        cvec, ND0, partial, H0S, z1b, Z1S, ND0);

    // --- Layer 2
    node_proj<<<dim3((NS1 + NP_NPB - 1) / NP_NPB, 2), 256, 0, stream>>>(
        z1b, Z1S, ea2, ia2, ecor, esim, pd, qd, NS1, ND1);
    edge_gather4<<<dim3((ND1 + 3) / 4, 2), 256, 0, stream>>>(
        z1b, Z1S, ecor, esim, pd, qd, row_c1, src_c1, row_s1, src_s1,
        h0b, partial, cvec, ND1);
    mfma_gemm<128, 128, 2><<<dim3((ND1 + 127) / 128, 2), 256, 0, stream>>>(
        h0b, H0S, Wt2, (size_t)D_DIM * D_DIM, b2, D_DIM,
        cvec, ND0, partial, H0S, z2b, Z2S, ND1);

    // --- Output: out[m] = z2 @ Wout[m] + bout[m]  (fp32 out)
    mfma_gemm<64, 128, 1><<<dim3((ND1 + 127) / 128, 2), 256, 0, stream>>>(
        z2b, Z2S, Wtout, (size_t)O_DIM * D_DIM, bout, O_DIM,
        nullptr, 0, nullptr, 0, (float*)d_out, (size_t)ND1 * O_DIM, ND1);
}

// Round 6
// 553.894 us; speedup vs baseline: 1.0203x; 1.0203x over previous
//
#include <hip/hip_runtime.h>
#include <hip/hip_bf16.h>
#include <math.h>

// Problem constants (fixed by setup_inputs())
#define F_DIM 256
#define D_DIM 128
#define O_DIM 64
#define NS0   100000
#define ND0   25000
#define E0_N  500000
#define NS1   25000
#define ND1   5000
#define E1_N  100000

#define NBE0  1954   // ceil(E0_N/256)
#define NBE1  391    // ceil(E1_N/256)
#define NB_CSR (2 * NBE0 + 2 * NBE1)
#define NB_WPREP 576

typedef __attribute__((ext_vector_type(8))) short s8v;   // 8 bf16 (4 VGPRs)
typedef __attribute__((ext_vector_type(4))) float f4v;   // 4 fp32 acc

struct CPtr4 { const int *p0, *p1, *p2, *p3; };
struct MPtr4 { int *p0, *p1, *p2, *p3; };

__device__ __forceinline__ float2 unpack2(uint u) {
    union { uint i; float f; } a, b;
    a.i = (u & 0xffffu) << 16; b.i = u & 0xffff0000u;
    return make_float2(a.f, b.f);
}
__device__ __forceinline__ ushort f2bf(float f) {
    __hip_bfloat16 h = __float2bfloat16(f);
    return *(ushort*)&h;
}
__device__ __forceinline__ float u2f(uint u) {
    union { uint i; float f; } v; v.i = u; return v.f;
}
__device__ __forceinline__ uint f2u(float f) {
    union { uint i; float f; } v; v.f = f; return v.i;
}

// ---------------------------------------------------------------------------
// Layer-0 GEMM, dual-mode A-sharing: stage fp32 feat chunk ONCE, multiply by
// both modes' Wtin. Block = 64 rows x 128 cols x 2 modes. 4 waves (2x2).
// (UNFUSED version -- R5's node_proj fusion caused 16-way LDS bank conflicts
//  on the zs stash (row stride 256B -> banks {0,8,16,24}) + occupancy loss.)
// ---------------------------------------------------------------------------
__global__ __launch_bounds__(256) void gemm_l0(
    const float* __restrict__ A,          // feat [M][256] fp32
    const ushort* __restrict__ Btb,       // Wtin [2][128][256] bf16
    const float* __restrict__ biasb,      // b_in [2][128]
    ushort* __restrict__ Coutb, size_t coutstr, int M)
{
    constexpr int PA = 40;
    __shared__ ushort As[64 * PA];
    __shared__ ushort Bs[2][128 * PA];

    const int tid = threadIdx.x;
    const int row0 = blockIdx.x * 64;
    const int wave = tid >> 6, lane = tid & 63;
    const int l15 = lane & 15, l4 = lane >> 4;
    const int wm0 = (wave >> 1) * 32;   // 0 or 32
    const int wn0 = (wave & 1) * 64;    // 0 or 64

    f4v acc[2][2][4];
    #pragma unroll
    for (int m2 = 0; m2 < 2; ++m2)
        #pragma unroll
        for (int i = 0; i < 2; ++i)
            #pragma unroll
            for (int j = 0; j < 4; ++j)
                acc[m2][i][j] = (f4v)(0.0f);

    for (int kc = 0; kc < F_DIM; kc += 32) {
        __syncthreads();
        // A chunk: 64 rows x 32 fp32 -> bf16 (one 8-elem group per thread)
        {
            int r = tid >> 2, g = (tid & 3) * 8;
            int gr = row0 + r;
            float4 v0 = make_float4(0.f, 0.f, 0.f, 0.f);
            float4 v1 = make_float4(0.f, 0.f, 0.f, 0.f);
            if (gr < M) {
                v0 = *(const float4*)(A + (size_t)gr * F_DIM + kc + g);
                v1 = *(const float4*)(A + (size_t)gr * F_DIM + kc + g + 4);
            }
            ushort4 o0, o1;
            o0.x = f2bf(v0.x); o0.y = f2bf(v0.y); o0.z = f2bf(v0.z); o0.w = f2bf(v0.w);
            o1.x = f2bf(v1.x); o1.y = f2bf(v1.y); o1.z = f2bf(v1.z); o1.w = f2bf(v1.w);
            *(ushort4*)(&As[r * PA + g]) = o0;
            *(ushort4*)(&As[r * PA + g + 4]) = o1;
        }
        // B chunks: both modes, 128 rows x 32 bf16 each
        #pragma unroll
        for (int m2 = 0; m2 < 2; ++m2)
            #pragma unroll
            for (int it = 0; it < 2; ++it) {
                int f = tid + it * 256;
                int r = f >> 2, g = (f & 3) * 8;
                *(float4*)(&Bs[m2][r * PA + g]) =
                    *(const float4*)(Btb + m2 * (D_DIM * F_DIM) + (size_t)r * F_DIM + kc + g);
            }
        __syncthreads();

        s8v af[2];
        #pragma unroll
        for (int i = 0; i < 2; ++i)
            af[i] = *(const s8v*)(&As[(wm0 + i * 16 + l15) * PA + l4 * 8]);
        #pragma unroll
        for (int m2 = 0; m2 < 2; ++m2) {
            s8v bfr[4];
            #pragma unroll
            for (int j = 0; j < 4; ++j)
                bfr[j] = *(const s8v*)(&Bs[m2][(wn0 + j * 16 + l15) * PA + l4 * 8]);
            #pragma unroll
            for (int i = 0; i < 2; ++i)
                #pragma unroll
                for (int j = 0; j < 4; ++j)
                    acc[m2][i][j] = __builtin_amdgcn_mfma_f32_16x16x32_bf16(
                        af[i], bfr[j], acc[m2][i][j], 0, 0, 0);
        }
    }

    #pragma unroll
    for (int m2 = 0; m2 < 2; ++m2)
        #pragma unroll
        for (int i = 0; i < 2; ++i)
            #pragma unroll
            for (int ii = 0; ii < 4; ++ii) {
                int row = row0 + wm0 + i * 16 + l4 * 4 + ii;
                if (row < M) {
                    #pragma unroll
                    for (int j = 0; j < 4; ++j) {
                        int col = wn0 + j * 16 + l15;
                        Coutb[m2 * coutstr + (size_t)row * D_DIM + col] =
                            f2bf(acc[m2][i][j][ii] + biasb[m2 * D_DIM + col]);
                    }
                }
            }
}

// ---------------------------------------------------------------------------
// MFMA bf16 GEMM, mode-fused (blockIdx.y = m), bf16 A.
// EPI 1: +bias -> f32
// EPI 2 (agg-fused): out = partial + 0.5*relu(acc + c[row]*bias[col]) -> bf16
// ---------------------------------------------------------------------------
template<int NW, int KD, int EPI>
__global__ __launch_bounds__(256) void mfma_gemm(
    const ushort* __restrict__ Ab, size_t astr,
    const ushort* __restrict__ Btb, size_t btstr,
    const float* __restrict__ biasb, size_t bstr,
    const float* __restrict__ cvecb, size_t cvstr,
    const float* __restrict__ partialb, size_t pstr,
    void* __restrict__ Coutb, size_t coutstr, int M)
{
    const int m = blockIdx.y;
    const ushort* A = Ab + m * astr;
    const ushort* Bt = Btb + m * btstr;
    const float* bias = biasb + m * bstr;
    const float* cvec = (EPI == 2) ? cvecb + m * cvstr : nullptr;
    const float* partial = (EPI == 2) ? partialb + m * pstr : nullptr;
    char* Cout = (char*)Coutb + m * coutstr * (EPI == 1 ? 4 : 2);

    constexpr int PA = 40;
    constexpr int WAVES_M = (NW == 128) ? 2 : 4;
    constexpr int WM = 128 / WAVES_M;
    constexpr int TM = WM / 16;
    constexpr int TN = 4;
    __shared__ ushort As[128 * PA];
    __shared__ ushort Bs[NW * PA];

    const int tid  = threadIdx.x;
    const int row0 = blockIdx.x * 128;
    const int wave = tid >> 6, lane = tid & 63;
    const int l15 = lane & 15, l4 = lane >> 4;
    int wm0, wn0;
    if (NW == 128) { wm0 = (wave >> 1) * 64; wn0 = (wave & 1) * 64; }
    else           { wm0 = wave * WM;        wn0 = 0; }

    f4v acc[TM][TN];
    #pragma unroll
    for (int i = 0; i < TM; ++i)
        #pragma unroll
        for (int j = 0; j < TN; ++j)
            acc[i][j] = (f4v)(0.0f);

    for (int kc = 0; kc < KD; kc += 32) {
        __syncthreads();
        #pragma unroll
        for (int it = 0; it < 2; ++it) {
            int f = tid + it * 256;
            int r = f >> 2, g = (f & 3) * 8;
            int gr = row0 + r;
            float4 v = make_float4(0.f, 0.f, 0.f, 0.f);
            if (gr < M) v = *(const float4*)(A + (size_t)gr * KD + kc + g);
            *(float4*)(&As[r * PA + g]) = v;
        }
        #pragma unroll
        for (int it = 0; it < NW * 32 / (256 * 8); ++it) {
            int f = tid + it * 256;
            int r = f >> 2, g = (f & 3) * 8;
            *(float4*)(&Bs[r * PA + g]) = *(const float4*)(Bt + (size_t)r * KD + kc + g);
        }
        __syncthreads();

        s8v af[TM], bfr[TN];
        #pragma unroll
        for (int i = 0; i < TM; ++i)
            af[i] = *(const s8v*)(&As[(wm0 + i * 16 + l15) * PA + l4 * 8]);
        #pragma unroll
        for (int j = 0; j < TN; ++j)
            bfr[j] = *(const s8v*)(&Bs[(wn0 + j * 16 + l15) * PA + l4 * 8]);
        #pragma unroll
        for (int i = 0; i < TM; ++i)
            #pragma unroll
            for (int j = 0; j < TN; ++j)
                acc[i][j] = __builtin_amdgcn_mfma_f32_16x16x32_bf16(
                    af[i], bfr[j], acc[i][j], 0, 0, 0);
    }

    #pragma unroll
    for (int i = 0; i < TM; ++i) {
        #pragma unroll
        for (int ii = 0; ii < 4; ++ii) {
            int row = row0 + wm0 + i * 16 + l4 * 4 + ii;
            if (row < M) {
                #pragma unroll
                for (int j = 0; j < TN; ++j) {
                    int col = wn0 + j * 16 + l15;
                    float a = acc[i][j][ii];
                    if (EPI == 1) {
                        ((float*)Cout)[(size_t)row * NW + col] = a + bias[col];
                    } else {
                        float val = a + cvec[row] * bias[col];
                        float o = partial[(size_t)row * NW + col] + 0.5f * fmaxf(val, 0.f);
                        ((ushort*)Cout)[(size_t)row * NW + col] = f2bf(o);
                    }
                }
            }
        }
    }
}

// ---------------------------------------------------------------------------
// CSR histogram (4 edge lists batched) + weight transpose merged in one grid.
// ---------------------------------------------------------------------------
__global__ void histo4_prep(CPtr4 ed, MPtr4 cnt,
    const float* __restrict__ Win, const float* __restrict__ W1,
    const float* __restrict__ W2,  const float* __restrict__ Wout,
    ushort* __restrict__ Wtin, ushort* __restrict__ Wt1,
    ushort* __restrict__ Wt2,  ushort* __restrict__ Wtout)
{
    int b = blockIdx.x, t = threadIdx.x;
    if (b >= NB_CSR) {
        int i = (b - NB_CSR) * 256 + t;
        if (i < 65536) {
            int m = i >> 15, r = i & 32767, k = r >> 7, n = r & 127;
            Wtin[m * 32768 + n * 256 + k] = f2bf(Win[m * 32768 + k * 128 + n]);
        } else if (i < 98304) {
            int i2 = i - 65536;
            int m = i2 >> 14, r = i2 & 16383, k = r >> 7, n = r & 127;
            Wt1[m * 16384 + n * 128 + k] = f2bf(W1[m * 16384 + k * 128 + n]);
        } else if (i < 131072) {
            int i2 = i - 98304;
            int m = i2 >> 14, r = i2 & 16383, k = r >> 7, n = r & 127;
            Wt2[m * 16384 + n * 128 + k] = f2bf(W2[m * 16384 + k * 128 + n]);
        } else if (i < 147456) {
            int i2 = i - 131072;
            int m = i2 >> 13, r = i2 & 8191, k = r >> 6, n = r & 63;
            Wtout[m * 8192 + n * 128 + k] = f2bf(Wout[m * 8192 + k * 64 + n]);
        }
        return;
    }
    const int* edp; int* cp; int e, E;
    if (b < NBE0)          { edp = ed.p0; cp = cnt.p0; e = b * 256 + t;              E = E0_N; }
    else if (b < 2 * NBE0) { edp = ed.p1; cp = cnt.p1; e = (b - NBE0) * 256 + t;     E = E0_N; }
    else if (b < 2 * NBE0 + NBE1)
                           { edp = ed.p2; cp = cnt.p2; e = (b - 2 * NBE0) * 256 + t; E = E1_N; }
    else                   { edp = ed.p3; cp = cnt.p3; e = (b - 2 * NBE0 - NBE1) * 256 + t; E = E1_N; }
    if (e < E) atomicAdd(&cp[edp[e]], 1);
}

__global__ __launch_bounds__(1024) void exscan4(MPtr4 cnt, MPtr4 row, MPtr4 head)
{
    __shared__ int part[1024];
    const int b = blockIdx.x, t = threadIdx.x;
    int* cp; int* rp; int* hp; int n;
    if (b == 0)      { cp = cnt.p0; rp = row.p0; hp = head.p0; n = ND0; }
    else if (b == 1) { cp = cnt.p1; rp = row.p1; hp = head.p1; n = ND0; }
    else if (b == 2) { cp = cnt.p2; rp = row.p2; hp = head.p2; n = ND1; }
    else             { cp = cnt.p3; rp = row.p3; hp = head.p3; n = ND1; }

    const int chunk = (n + 1023) >> 10;
    const int start = t * chunk;
    int s = 0;
    for (int i = 0; i < chunk; ++i) {
        int idx = start + i;
        if (idx < n) s += cp[idx];
    }
    part[t] = s;
    __syncthreads();
    for (int off = 1; off < 1024; off <<= 1) {
        int v = (t >= off) ? part[t - off] : 0;
        __syncthreads();
        part[t] += v;
        __syncthreads();
    }
    int run = (t == 0) ? 0 : part[t - 1];
    for (int i = 0; i < chunk; ++i) {
        int idx = start + i;
        if (idx < n) { rp[idx] = run; hp[idx] = run; run += cp[idx]; }
    }
    if (t == 1023) rp[n] = part[1023];
}

__global__ void build4(CPtr4 es, CPtr4 ed, MPtr4 head, MPtr4 src)
{
    int b = blockIdx.x, t = threadIdx.x;
    const int *esp, *edp; int *hp, *sp; int e, E;
    if (b < NBE0)          { esp = es.p0; edp = ed.p0; hp = head.p0; sp = src.p0; e = b * 256 + t;              E = E0_N; }
    else if (b < 2 * NBE0) { esp = es.p1; edp = ed.p1; hp = head.p1; sp = src.p1; e = (b - NBE0) * 256 + t;     E = E0_N; }
    else if (b < 2 * NBE0 + NBE1)
                           { esp = es.p2; edp = ed.p2; hp = head.p2; sp = src.p2; e = (b - 2 * NBE0) * 256 + t; E = E1_N; }
    else                   { esp = es.p3; edp = ed.p3; hp = head.p3; sp = src.p3; e = (b - 2 * NBE0 - NBE1) * 256 + t; E = E1_N; }
    if (e >= E) return;
    int p = atomicAdd(&hp[edp[e]], 1);
    sp[p] = esp[e];
}

// ---------------------------------------------------------------------------
// Per-node projections, mode-fused. 8 lanes/node, weight slices in regs.
// Writes PACKED per-src tables for the fused edge kernel:
//   ecor[s] = { p0_m0, p1_m0, q_m1, - }   (cor list: e-ch mode0, i-ch mode1)
//   esim[s] = { p0_m1, p1_m1, q_m0, - }   (sim list: e-ch mode1, i-ch mode0)
// dst-side components stay in pd/qd with ND0 mode stride.
// ---------------------------------------------------------------------------
#define NP_NPB 128
__global__ __launch_bounds__(256) void node_proj(
    const ushort* __restrict__ zb, size_t zstr,
    const float* __restrict__ Web, const float* __restrict__ Wib,
    float4* __restrict__ ecor, float4* __restrict__ esim,
    float* __restrict__ pdb, float* __restrict__ qdb,
    int n_src, int n_dst)
{
    const int m = blockIdx.y;
    const ushort* z = zb + m * zstr;
    const float* We = Web + m * 512;
    const float* Wi = Wib + m * 256;

    __shared__ float w[6][D_DIM];
    for (int k = threadIdx.x; k < D_DIM; k += 256) {
        w[0][k] = We[k * 2 + 0];
        w[1][k] = We[k * 2 + 1];
        w[2][k] = Wi[k];
        w[3][k] = We[(D_DIM + k) * 2 + 0];
        w[4][k] = We[(D_DIM + k) * 2 + 1];
        w[5][k] = Wi[D_DIM + k];
    }
    __syncthreads();

    const int sub = threadIdx.x & 7;
    const int g   = threadIdx.x >> 3;

    float wr[6][16];
    #pragma unroll
    for (int c = 0; c < 6; ++c)
        #pragma unroll
        for (int q = 0; q < 4; ++q) {
            float4 f = *(const float4*)(&w[c][sub * 16 + q * 4]);
            wr[c][q * 4 + 0] = f.x; wr[c][q * 4 + 1] = f.y;
            wr[c][q * 4 + 2] = f.z; wr[c][q * 4 + 3] = f.w;
        }

    #pragma unroll
    for (int it = 0; it < 4; ++it) {
        int node = blockIdx.x * NP_NPB + it * 32 + g;
        if (node >= n_src) continue;
        const ushort* zp = z + (size_t)node * D_DIM + sub * 16;
        uint4 ra = *(const uint4*)zp;
        uint4 rb = *(const uint4*)(zp + 8);
        uint rr[8] = {ra.x, ra.y, ra.z, ra.w, rb.x, rb.y, rb.z, rb.w};
        float p[6] = {0.f, 0.f, 0.f, 0.f, 0.f, 0.f};
        #pragma unroll
        for (int e = 0; e < 8; ++e) {
            float2 f2 = unpack2(rr[e]);
            #pragma unroll
            for (int c = 0; c < 6; ++c)
                p[c] += f2.x * wr[c][2 * e] + f2.y * wr[c][2 * e + 1];
        }
        #pragma unroll
        for (int off = 4; off > 0; off >>= 1)
            #pragma unroll
            for (int c = 0; c < 6; ++c)
                p[c] += __shfl_down(p[c], off);

        if (sub == 0) {
            if (m == 0) {
                *(float2*)&ecor[node] = make_float2(p[0], p[1]);
                ((float*)&esim[node])[2] = p[2];
            } else {
                *(float2*)&esim[node] = make_float2(p[0], p[1]);
                ((float*)&ecor[node])[2] = p[2];
            }
            if (node < n_dst) {
                *(float2*)(pdb + (size_t)m * ND0 * 2 + 2 * (size_t)node) = make_float2(p[3], p[4]);
                qdb[(size_t)m * ND0 + node] = p[5];
            }
        }
    }
}

// ---------------------------------------------------------------------------
// FUSED edge attention + gather, per-(dst, mode) wave (blockIdx.y = mode).
// R1-measured-best structure (82.9us @ 270MB FETCH): sequential e-loop then
// i-loop, chunked, single LDS scratch, unpredicated full batches +
// predicated tail. Packed ecor/esim tables for 8B/4B phase-A gathers.
// ---------------------------------------------------------------------------
__global__ __launch_bounds__(256) void edge_gather4(
    const ushort* __restrict__ zb, size_t zstr,
    const float4* __restrict__ ecor, const float4* __restrict__ esim,
    const float* __restrict__ pdb, const float* __restrict__ qdb,
    const int* __restrict__ row_c, const int* __restrict__ src_c,
    const int* __restrict__ row_s, const int* __restrict__ src_s,
    ushort* __restrict__ h0base, float* __restrict__ partialb,
    float* __restrict__ cvecb, int n_dst)
{
    __shared__ uint2 sc[4][64];   // per-wave (weight, src) scratch

    const int m = blockIdx.y;
    const int wv = threadIdx.x >> 6;
    const int d = blockIdx.x * 4 + wv;
    const int lane = threadIdx.x & 63;
    if (d >= n_dst) return;

    const ushort* z = zb + (size_t)m * zstr;
    const ushort* zlane = z + lane * 2;

    const int* erow = m ? row_s : row_c;
    const int* esrc = m ? src_s : src_c;
    const int* irow = m ? row_c : row_s;
    const int* isrc = m ? src_c : src_s;
    const float4* etab = m ? esim : ecor;   // .xy = e-logits for mode m
    const float4* itab = m ? ecor : esim;   // .z  = i-logit  for mode m

    const float pd0 = pdb[(size_t)m * ND0 * 2 + 2 * d];
    const float pd1 = pdb[(size_t)m * ND0 * 2 + 2 * d + 1];
    const float qdd = qdb[(size_t)m * ND0 + d];

    float h0x = 0.f, h0y = 0.f, szx = 0.f, szy = 0.f;
    float ihx = 0.f, ihy = 0.f;
    float se0 = 0.f;

    // ---- e-channel loop
    const int b0 = erow[d], b1 = erow[d + 1];
    for (int base = b0; base < b1; base += 64) {
        const int cnt = min(64, b1 - base);
        if (lane < cnt) {
            int s = esrc[base + lane];
            float2 t = *(const float2*)&etab[s];
            float l0 = t.x + pd0, l1 = t.y + pd1;
            float mx = fmaxf(l0, l1);
            float x0 = __expf(l0 - mx), x1 = __expf(l1 - mx);
            float e0 = x0 / (x0 + x1);
            sc[wv][lane] = make_uint2(f2u(e0), (uint)s);
            se0 += e0;
        }
        asm volatile("s_waitcnt lgkmcnt(0)" ::: "memory");
        const int kf = cnt & ~7;
        int k = 0;
        for (; k < kf; k += 8) {
            uint2 ew[8]; uint rr[8];
            #pragma unroll
            for (int t = 0; t < 8; ++t) ew[t] = sc[wv][k + t];
            #pragma unroll
            for (int t = 0; t < 8; ++t) rr[t] = *(const uint*)(zlane + (size_t)ew[t].y * D_DIM);
            #pragma unroll
            for (int t = 0; t < 8; ++t) {
                float w0 = u2f(ew[t].x);
                float2 v = unpack2(rr[t]);
                szx += v.x; szy += v.y;
                h0x += w0 * v.x; h0y += w0 * v.y;
            }
        }
        if (k < cnt) {   // predicated batch of 8
            uint2 ew[8]; uint rr[8];
            #pragma unroll
            for (int t = 0; t < 8; ++t) ew[t] = sc[wv][(k + t) & 63];
            #pragma unroll
            for (int t = 0; t < 8; ++t) {
                uint s = (k + t < cnt) ? ew[t].y : 0u;
                rr[t] = *(const uint*)(zlane + (size_t)s * D_DIM);
            }
            #pragma unroll
            for (int t = 0; t < 8; ++t) {
                float sel = (k + t < cnt) ? 1.0f : 0.0f;
                float w0 = u2f(ew[t].x) * sel;
                float2 v = unpack2(rr[t]);
                szx += v.x * sel; szy += v.y * sel;
                h0x += w0 * v.x; h0y += w0 * v.y;
            }
        }
    }

    // cvec = (sum e0) / deg
    #pragma unroll
    for (int off = 32; off > 0; off >>= 1)
        se0 += __shfl_down(se0, off);
    if (lane == 0)
        cvecb[(size_t)m * ND0 + d] = se0 / fmaxf((float)(b1 - b0), 1.0f);

    // ---- i-channel loop
    const int c0 = irow[d], c1 = irow[d + 1];
    for (int base = c0; base < c1; base += 64) {
        const int cnt = min(64, c1 - base);
        if (lane < cnt) {
            int s = isrc[base + lane];
            float ti = ((const float*)&itab[s])[2];
            float sg = 1.0f / (1.0f + __expf(-(ti + qdd)));
            sc[wv][lane] = make_uint2(f2u(sg), (uint)s);
        }
        asm volatile("s_waitcnt lgkmcnt(0)" ::: "memory");
        const int kf = cnt & ~7;
        int k = 0;
        for (; k < kf; k += 8) {
            uint2 ew[8]; uint rr[8];
            #pragma unroll
            for (int t = 0; t < 8; ++t) ew[t] = sc[wv][k + t];
            #pragma unroll
            for (int t = 0; t < 8; ++t) rr[t] = *(const uint*)(zlane + (size_t)ew[t].y * D_DIM);
            #pragma unroll
            for (int t = 0; t < 8; ++t) {
                float g = u2f(ew[t].x);
                float2 v = unpack2(rr[t]);
                ihx += g * v.x; ihy += g * v.y;
            }
        }
        if (k < cnt) {
            uint2 ew[8]; uint rr[8];
            #pragma unroll
            for (int t = 0; t < 8; ++t) ew[t] = sc[wv][(k + t) & 63];
            #pragma unroll
            for (int t = 0; t < 8; ++t) {
                uint s = (k + t < cnt) ? ew[t].y : 0u;
                rr[t] = *(const uint*)(zlane + (size_t)s * D_DIM);
            }
            #pragma unroll
            for (int t = 0; t < 8; ++t) {
                float sel = (k + t < cnt) ? 1.0f : 0.0f;
                float g = u2f(ew[t].x) * sel;
                float2 v = unpack2(rr[t]);
                ihx += g * v.x; ihy += g * v.y;
            }
        }
    }

    // ---- epilogue
    const int nE = b1 - b0;
    float ehx = szx - h0x, ehy = szy - h0y;   // e1 = 1 - e0
    float inv = 1.0f / fmaxf((float)nE, 1.0f);
    uint hp = (uint)f2bf(h0x * inv) | ((uint)f2bf(h0y * inv) << 16);
    const size_t MSTR = (size_t)ND0 * D_DIM;
    *(uint*)(h0base + (size_t)m * MSTR + (size_t)d * D_DIM + lane * 2) = hp;

    float2 zd = unpack2(*(const uint*)(zlane + (size_t)d * D_DIM));
    float px = 0.5f * (fmaxf(ehx * ihx, 0.f) + zd.x);
    float py = 0.5f * (fmaxf(ehy * ihy, 0.f) + zd.y);
    *(float2*)(partialb + (size_t)m * MSTR + (size_t)d * D_DIM + lane * 2) =
        make_float2(px, py);
}

// ---------------------------------------------------------------------------
extern "C" void kernel_launch(void* const* d_in, const int* in_sizes, int n_in,
                              void* d_out, int out_size, void* d_ws, size_t ws_size,
                              hipStream_t stream)
{
    const float* feat = (const float*)d_in[0];
    const int* src0_cor = (const int*)d_in[1];
    const int* dst0_cor = (const int*)d_in[2];
    const int* src0_sim = (const int*)d_in[3];
    const int* dst0_sim = (const int*)d_in[4];
    const int* src1_cor = (const int*)d_in[5];
    const int* dst1_cor = (const int*)d_in[6];
    const int* src1_sim = (const int*)d_in[7];
    const int* dst1_sim = (const int*)d_in[8];
    const float* Win  = (const float*)d_in[11];
    const float* b_in = (const float*)d_in[12];
    const float* ea1  = (const float*)d_in[14];
    const float* ia1  = (const float*)d_in[15];
    const float* W1   = (const float*)d_in[16];
    const float* b1   = (const float*)d_in[17];
    const float* ea2  = (const float*)d_in[19];
    const float* ia2  = (const float*)d_in[20];
    const float* W2   = (const float*)d_in[21];
    const float* b2   = (const float*)d_in[22];
    const float* Wout = (const float*)d_in[23];
    const float* bout = (const float*)d_in[24];
    (void)in_sizes; (void)n_in; (void)out_size; (void)ws_size;

    // ---- workspace layout ----
    char* wsb = (char*)d_ws;
    size_t off = 0;
    auto alloc_f  = [&](size_t n) { float*  p = (float*) (wsb + off); off += n * 4; return p; };
    auto alloc_f4 = [&](size_t n) { float4* p = (float4*)(wsb + off); off += n * 16; return p; };
    auto alloc_i  = [&](size_t n) { int*    p = (int*)   (wsb + off); off += n * 4; return p; };
    auto alloc_h  = [&](size_t n) { ushort* p = (ushort*)(wsb + off); off += ((n * 2 + 15) & ~15ull); return p; };

    ushort* z0b   = alloc_h((size_t)2 * NS0 * D_DIM);
    ushort* z1b   = alloc_h((size_t)2 * NS1 * D_DIM);
    ushort* z2b   = alloc_h((size_t)2 * ND1 * D_DIM);
    ushort* h0b   = alloc_h((size_t)2 * ND0 * D_DIM);
    ushort* Wtin  = alloc_h((size_t)2 * D_DIM * F_DIM);
    ushort* Wt1   = alloc_h((size_t)2 * D_DIM * D_DIM);
    ushort* Wt2   = alloc_h((size_t)2 * D_DIM * D_DIM);
    ushort* Wtout = alloc_h((size_t)2 * O_DIM * D_DIM);

    float4* ecor   = alloc_f4((size_t)NS0);
    float4* esim   = alloc_f4((size_t)NS0);
    float* pd      = alloc_f((size_t)2 * ND0 * 2);
    float* qd      = alloc_f((size_t)2 * ND0);
    float* cvec    = alloc_f((size_t)2 * ND0);
    float* partial = alloc_f((size_t)2 * ND0 * D_DIM);

    int* src_c0 = alloc_i(E0_N); int* row_c0 = alloc_i(ND0 + 1);
    int* src_s0 = alloc_i(E0_N); int* row_s0 = alloc_i(ND0 + 1);
    int* src_c1 = alloc_i(E1_N); int* row_c1 = alloc_i(ND1 + 1);
    int* src_s1 = alloc_i(E1_N); int* row_s1 = alloc_i(ND1 + 1);
    int* cnt_all  = alloc_i(2 * ND0 + 2 * ND1);
    int* head_all = alloc_i(2 * ND0 + 2 * ND1);

    int* cnt_c0 = cnt_all;            int* head_c0 = head_all;
    int* cnt_s0 = cnt_all + ND0;      int* head_s0 = head_all + ND0;
    int* cnt_c1 = cnt_all + 2 * ND0;  int* head_c1 = head_all + 2 * ND0;
    int* cnt_s1 = cnt_c1 + ND1;       int* head_s1 = head_c1 + ND1;

    // ---- batched CSR build + weight prep ----
    hipMemsetAsync(cnt_all, 0, (size_t)(2 * ND0 + 2 * ND1) * 4, stream);
    {
        CPtr4 edp  = {dst0_cor, dst0_sim, dst1_cor, dst1_sim};
        CPtr4 esp  = {src0_cor, src0_sim, src1_cor, src1_sim};
        MPtr4 cntp = {cnt_c0, cnt_s0, cnt_c1, cnt_s1};
        MPtr4 rowp = {row_c0, row_s0, row_c1, row_s1};
        MPtr4 hdp  = {head_c0, head_s0, head_c1, head_s1};
        MPtr4 srcp = {src_c0, src_s0, src_c1, src_s1};
        histo4_prep<<<NB_CSR + NB_WPREP, 256, 0, stream>>>(
            edp, cntp, Win, W1, W2, Wout, Wtin, Wt1, Wt2, Wtout);
        exscan4<<<4, 1024, 0, stream>>>(cntp, rowp, hdp);
        build4<<<NB_CSR, 256, 0, stream>>>(esp, edp, hdp, srcp);
    }

    // ======== both modes fused ========
    const size_t Z0S = (size_t)NS0 * D_DIM, Z1S = (size_t)NS1 * D_DIM;
    const size_t Z2S = (size_t)ND1 * D_DIM, H0S = (size_t)ND0 * D_DIM;

    // --- Layer 0: z0[m] = feat @ Win[m] + b_in[m]  (A staged once for both modes)
    gemm_l0<<<(NS0 + 63) / 64, 256, 0, stream>>>(
        feat, Wtin, b_in, z0b, Z0S, NS0);

    // --- Layer 1
    node_proj<<<dim3((NS0 + NP_NPB - 1) / NP_NPB, 2), 256, 0, stream>>>(
        z0b, Z0S, ea1, ia1, ecor, esim, pd, qd, NS0, ND0);
    edge_gather4<<<dim3((ND0 + 3) / 4, 2), 256, 0, stream>>>(
        z0b, Z0S, ecor, esim, pd, qd, row_c0, src_c0, row_s0, src_s0,
        h0b, partial, cvec, ND0);
    mfma_gemm<128, 128, 2><<<dim3((ND0 + 127) / 128, 2), 256, 0, stream>>>(
        h0b, H0S, Wt1, (size_t)D_DIM * D_DIM, b1, D_DIM,
        cvec, ND0, partial, H0S, z1b, Z1S, ND0);

    // --- Layer 2
    node_proj<<<dim3((NS1 + NP_NPB - 1) / NP_NPB, 2), 256, 0, stream>>>(
        z1b, Z1S, ea2, ia2, ecor, esim, pd, qd, NS1, ND1);
    edge_gather4<<<dim3((ND1 + 3) / 4, 2), 256, 0, stream>>>(
        z1b, Z1S, ecor, esim, pd, qd, row_c1, src_c1, row_s1, src_s1,
        h0b, partial, cvec, ND1);
    mfma_gemm<128, 128, 2><<<dim3((ND1 + 127) / 128, 2), 256, 0, stream>>>(
        h0b, H0S, Wt2, (size_t)D_DIM * D_DIM, b2, D_DIM,
        cvec, ND0, partial, H0S, z2b, Z2S, ND1);

    // --- Output: out[m] = z2 @ Wout[m] + bout[m]  (fp32 out)
    mfma_gemm<64, 128, 1><<<dim3((ND1 + 127) / 128, 2), 256, 0, stream>>>(
        z2b, Z2S, Wtout, (size_t)O_DIM * D_DIM, bout, O_DIM,
        nullptr, 0, nullptr, 0, (float*)d_out, (size_t)ND1 * O_DIM, ND1);
}

// Round 7
// 535.969 us; speedup vs baseline: 1.0544x; 1.0334x over previous
//
#include <hip/hip_runtime.h>
#include <hip/hip_bf16.h>
#include <math.h>

// Problem constants (fixed by setup_inputs())
#define F_DIM 256
#define D_DIM 128
#define O_DIM 64
#define NS0   100000
#define ND0   25000
#define E0_N  500000
#define NS1   25000
#define ND1   5000
#define E1_N  100000

#define NBE0  1954   // ceil(E0_N/256)
#define NBE1  391    // ceil(E1_N/256)
#define NB_CSR (2 * NBE0 + 2 * NBE1)
#define NB_WPREP 576

typedef __attribute__((ext_vector_type(8))) short s8v;   // 8 bf16 (4 VGPRs)
typedef __attribute__((ext_vector_type(4))) float f4v;   // 4 fp32 acc

struct CPtr4 { const int *p0, *p1, *p2, *p3; };
struct MPtr4 { int *p0, *p1, *p2, *p3; };

__device__ __forceinline__ float2 unpack2(uint u) {
    union { uint i; float f; } a, b;
    a.i = (u & 0xffffu) << 16; b.i = u & 0xffff0000u;
    return make_float2(a.f, b.f);
}
__device__ __forceinline__ ushort f2bf(float f) {
    __hip_bfloat16 h = __float2bfloat16(f);
    return *(ushort*)&h;
}
__device__ __forceinline__ float u2f(uint u) {
    union { uint i; float f; } v; v.i = u; return v.f;
}
__device__ __forceinline__ uint f2u(float f) {
    union { uint i; float f; } v; v.f = f; return v.i;
}

// ---------------------------------------------------------------------------
// Layer-0 GEMM, dual-mode A-sharing: stage fp32 feat chunk ONCE, multiply by
// both modes' Wtin. Block = 64 rows x 128 cols x 2 modes. 4 waves (2x2).
// ---------------------------------------------------------------------------
__global__ __launch_bounds__(256) void gemm_l0(
    const float* __restrict__ A,          // feat [M][256] fp32
    const ushort* __restrict__ Btb,       // Wtin [2][128][256] bf16
    const float* __restrict__ biasb,      // b_in [2][128]
    ushort* __restrict__ Coutb, size_t coutstr, int M)
{
    constexpr int PA = 40;
    __shared__ ushort As[64 * PA];
    __shared__ ushort Bs[2][128 * PA];

    const int tid = threadIdx.x;
    const int row0 = blockIdx.x * 64;
    const int wave = tid >> 6, lane = tid & 63;
    const int l15 = lane & 15, l4 = lane >> 4;
    const int wm0 = (wave >> 1) * 32;   // 0 or 32
    const int wn0 = (wave & 1) * 64;    // 0 or 64

    f4v acc[2][2][4];
    #pragma unroll
    for (int m2 = 0; m2 < 2; ++m2)
        #pragma unroll
        for (int i = 0; i < 2; ++i)
            #pragma unroll
            for (int j = 0; j < 4; ++j)
                acc[m2][i][j] = (f4v)(0.0f);

    for (int kc = 0; kc < F_DIM; kc += 32) {
        __syncthreads();
        // A chunk: 64 rows x 32 fp32 -> bf16 (one 8-elem group per thread)
        {
            int r = tid >> 2, g = (tid & 3) * 8;
            int gr = row0 + r;
            float4 v0 = make_float4(0.f, 0.f, 0.f, 0.f);
            float4 v1 = make_float4(0.f, 0.f, 0.f, 0.f);
            if (gr < M) {
                v0 = *(const float4*)(A + (size_t)gr * F_DIM + kc + g);
                v1 = *(const float4*)(A + (size_t)gr * F_DIM + kc + g + 4);
            }
            ushort4 o0, o1;
            o0.x = f2bf(v0.x); o0.y = f2bf(v0.y); o0.z = f2bf(v0.z); o0.w = f2bf(v0.w);
            o1.x = f2bf(v1.x); o1.y = f2bf(v1.y); o1.z = f2bf(v1.z); o1.w = f2bf(v1.w);
            *(ushort4*)(&As[r * PA + g]) = o0;
            *(ushort4*)(&As[r * PA + g + 4]) = o1;
        }
        // B chunks: both modes, 128 rows x 32 bf16 each
        #pragma unroll
        for (int m2 = 0; m2 < 2; ++m2)
            #pragma unroll
            for (int it = 0; it < 2; ++it) {
                int f = tid + it * 256;
                int r = f >> 2, g = (f & 3) * 8;
                *(float4*)(&Bs[m2][r * PA + g]) =
                    *(const float4*)(Btb + m2 * (D_DIM * F_DIM) + (size_t)r * F_DIM + kc + g);
            }
        __syncthreads();

        s8v af[2];
        #pragma unroll
        for (int i = 0; i < 2; ++i)
            af[i] = *(const s8v*)(&As[(wm0 + i * 16 + l15) * PA + l4 * 8]);
        #pragma unroll
        for (int m2 = 0; m2 < 2; ++m2) {
            s8v bfr[4];
            #pragma unroll
            for (int j = 0; j < 4; ++j)
                bfr[j] = *(const s8v*)(&Bs[m2][(wn0 + j * 16 + l15) * PA + l4 * 8]);
            #pragma unroll
            for (int i = 0; i < 2; ++i)
                #pragma unroll
                for (int j = 0; j < 4; ++j)
                    acc[m2][i][j] = __builtin_amdgcn_mfma_f32_16x16x32_bf16(
                        af[i], bfr[j], acc[m2][i][j], 0, 0, 0);
        }
    }

    #pragma unroll
    for (int m2 = 0; m2 < 2; ++m2)
        #pragma unroll
        for (int i = 0; i < 2; ++i)
            #pragma unroll
            for (int ii = 0; ii < 4; ++ii) {
                int row = row0 + wm0 + i * 16 + l4 * 4 + ii;
                if (row < M) {
                    #pragma unroll
                    for (int j = 0; j < 4; ++j) {
                        int col = wn0 + j * 16 + l15;
                        Coutb[m2 * coutstr + (size_t)row * D_DIM + col] =
                            f2bf(acc[m2][i][j][ii] + biasb[m2 * D_DIM + col]);
                    }
                }
            }
}

// ---------------------------------------------------------------------------
// MFMA bf16 GEMM, mode-fused (blockIdx.y = m), bf16 A.
// EPI 1: +bias -> f32
// EPI 2 (agg-fused): out = partial + 0.5*relu(acc + c[row]*bias[col]) -> bf16
// ---------------------------------------------------------------------------
template<int NW, int KD, int EPI>
__global__ __launch_bounds__(256) void mfma_gemm(
    const ushort* __restrict__ Ab, size_t astr,
    const ushort* __restrict__ Btb, size_t btstr,
    const float* __restrict__ biasb, size_t bstr,
    const float* __restrict__ cvecb, size_t cvstr,
    const float* __restrict__ partialb, size_t pstr,
    void* __restrict__ Coutb, size_t coutstr, int M)
{
    const int m = blockIdx.y;
    const ushort* A = Ab + m * astr;
    const ushort* Bt = Btb + m * btstr;
    const float* bias = biasb + m * bstr;
    const float* cvec = (EPI == 2) ? cvecb + m * cvstr : nullptr;
    const float* partial = (EPI == 2) ? partialb + m * pstr : nullptr;
    char* Cout = (char*)Coutb + m * coutstr * (EPI == 1 ? 4 : 2);

    constexpr int PA = 40;
    constexpr int WAVES_M = (NW == 128) ? 2 : 4;
    constexpr int WM = 128 / WAVES_M;
    constexpr int TM = WM / 16;
    constexpr int TN = 4;
    __shared__ ushort As[128 * PA];
    __shared__ ushort Bs[NW * PA];

    const int tid  = threadIdx.x;
    const int row0 = blockIdx.x * 128;
    const int wave = tid >> 6, lane = tid & 63;
    const int l15 = lane & 15, l4 = lane >> 4;
    int wm0, wn0;
    if (NW == 128) { wm0 = (wave >> 1) * 64; wn0 = (wave & 1) * 64; }
    else           { wm0 = wave * WM;        wn0 = 0; }

    f4v acc[TM][TN];
    #pragma unroll
    for (int i = 0; i < TM; ++i)
        #pragma unroll
        for (int j = 0; j < TN; ++j)
            acc[i][j] = (f4v)(0.0f);

    for (int kc = 0; kc < KD; kc += 32) {
        __syncthreads();
        #pragma unroll
        for (int it = 0; it < 2; ++it) {
            int f = tid + it * 256;
            int r = f >> 2, g = (f & 3) * 8;
            int gr = row0 + r;
            float4 v = make_float4(0.f, 0.f, 0.f, 0.f);
            if (gr < M) v = *(const float4*)(A + (size_t)gr * KD + kc + g);
            *(float4*)(&As[r * PA + g]) = v;
        }
        #pragma unroll
        for (int it = 0; it < NW * 32 / (256 * 8); ++it) {
            int f = tid + it * 256;
            int r = f >> 2, g = (f & 3) * 8;
            *(float4*)(&Bs[r * PA + g]) = *(const float4*)(Bt + (size_t)r * KD + kc + g);
        }
        __syncthreads();

        s8v af[TM], bfr[TN];
        #pragma unroll
        for (int i = 0; i < TM; ++i)
            af[i] = *(const s8v*)(&As[(wm0 + i * 16 + l15) * PA + l4 * 8]);
        #pragma unroll
        for (int j = 0; j < TN; ++j)
            bfr[j] = *(const s8v*)(&Bs[(wn0 + j * 16 + l15) * PA + l4 * 8]);
        #pragma unroll
        for (int i = 0; i < TM; ++i)
            #pragma unroll
            for (int j = 0; j < TN; ++j)
                acc[i][j] = __builtin_amdgcn_mfma_f32_16x16x32_bf16(
                    af[i], bfr[j], acc[i][j], 0, 0, 0);
    }

    #pragma unroll
    for (int i = 0; i < TM; ++i) {
        #pragma unroll
        for (int ii = 0; ii < 4; ++ii) {
            int row = row0 + wm0 + i * 16 + l4 * 4 + ii;
            if (row < M) {
                #pragma unroll
                for (int j = 0; j < TN; ++j) {
                    int col = wn0 + j * 16 + l15;
                    float a = acc[i][j][ii];
                    if (EPI == 1) {
                        ((float*)Cout)[(size_t)row * NW + col] = a + bias[col];
                    } else {
                        float val = a + cvec[row] * bias[col];
                        float o = partial[(size_t)row * NW + col] + 0.5f * fmaxf(val, 0.f);
                        ((ushort*)Cout)[(size_t)row * NW + col] = f2bf(o);
                    }
                }
            }
        }
    }
}

// ---------------------------------------------------------------------------
// CSR histogram (4 edge lists batched) + weight transpose merged in one grid.
// ---------------------------------------------------------------------------
__global__ void histo4_prep(CPtr4 ed, MPtr4 cnt,
    const float* __restrict__ Win, const float* __restrict__ W1,
    const float* __restrict__ W2,  const float* __restrict__ Wout,
    ushort* __restrict__ Wtin, ushort* __restrict__ Wt1,
    ushort* __restrict__ Wt2,  ushort* __restrict__ Wtout)
{
    int b = blockIdx.x, t = threadIdx.x;
    if (b >= NB_CSR) {
        int i = (b - NB_CSR) * 256 + t;
        if (i < 65536) {
            int m = i >> 15, r = i & 32767, k = r >> 7, n = r & 127;
            Wtin[m * 32768 + n * 256 + k] = f2bf(Win[m * 32768 + k * 128 + n]);
        } else if (i < 98304) {
            int i2 = i - 65536;
            int m = i2 >> 14, r = i2 & 16383, k = r >> 7, n = r & 127;
            Wt1[m * 16384 + n * 128 + k] = f2bf(W1[m * 16384 + k * 128 + n]);
        } else if (i < 131072) {
            int i2 = i - 98304;
            int m = i2 >> 14, r = i2 & 16383, k = r >> 7, n = r & 127;
            Wt2[m * 16384 + n * 128 + k] = f2bf(W2[m * 16384 + k * 128 + n]);
        } else if (i < 147456) {
            int i2 = i - 131072;
            int m = i2 >> 13, r = i2 & 8191, k = r >> 6, n = r & 63;
            Wtout[m * 8192 + n * 128 + k] = f2bf(Wout[m * 8192 + k * 64 + n]);
        }
        return;
    }
    const int* edp; int* cp; int e, E;
    if (b < NBE0)          { edp = ed.p0; cp = cnt.p0; e = b * 256 + t;              E = E0_N; }
    else if (b < 2 * NBE0) { edp = ed.p1; cp = cnt.p1; e = (b - NBE0) * 256 + t;     E = E0_N; }
    else if (b < 2 * NBE0 + NBE1)
                           { edp = ed.p2; cp = cnt.p2; e = (b - 2 * NBE0) * 256 + t; E = E1_N; }
    else                   { edp = ed.p3; cp = cnt.p3; e = (b - 2 * NBE0 - NBE1) * 256 + t; E = E1_N; }
    if (e < E) atomicAdd(&cp[edp[e]], 1);
}

__global__ __launch_bounds__(1024) void exscan4(MPtr4 cnt, MPtr4 row, MPtr4 head)
{
    __shared__ int part[1024];
    const int b = blockIdx.x, t = threadIdx.x;
    int* cp; int* rp; int* hp; int n;
    if (b == 0)      { cp = cnt.p0; rp = row.p0; hp = head.p0; n = ND0; }
    else if (b == 1) { cp = cnt.p1; rp = row.p1; hp = head.p1; n = ND0; }
    else if (b == 2) { cp = cnt.p2; rp = row.p2; hp = head.p2; n = ND1; }
    else             { cp = cnt.p3; rp = row.p3; hp = head.p3; n = ND1; }

    const int chunk = (n + 1023) >> 10;
    const int start = t * chunk;
    int s = 0;
    for (int i = 0; i < chunk; ++i) {
        int idx = start + i;
        if (idx < n) s += cp[idx];
    }
    part[t] = s;
    __syncthreads();
    for (int off = 1; off < 1024; off <<= 1) {
        int v = (t >= off) ? part[t - off] : 0;
        __syncthreads();
        part[t] += v;
        __syncthreads();
    }
    int run = (t == 0) ? 0 : part[t - 1];
    for (int i = 0; i < chunk; ++i) {
        int idx = start + i;
        if (idx < n) { rp[idx] = run; hp[idx] = run; run += cp[idx]; }
    }
    if (t == 1023) rp[n] = part[1023];
}

__global__ void build4(CPtr4 es, CPtr4 ed, MPtr4 head, MPtr4 src)
{
    int b = blockIdx.x, t = threadIdx.x;
    const int *esp, *edp; int *hp, *sp; int e, E;
    if (b < NBE0)          { esp = es.p0; edp = ed.p0; hp = head.p0; sp = src.p0; e = b * 256 + t;              E = E0_N; }
    else if (b < 2 * NBE0) { esp = es.p1; edp = ed.p1; hp = head.p1; sp = src.p1; e = (b - NBE0) * 256 + t;     E = E0_N; }
    else if (b < 2 * NBE0 + NBE1)
                           { esp = es.p2; edp = ed.p2; hp = head.p2; sp = src.p2; e = (b - 2 * NBE0) * 256 + t; E = E1_N; }
    else                   { esp = es.p3; edp = ed.p3; hp = head.p3; sp = src.p3; e = (b - 2 * NBE0 - NBE1) * 256 + t; E = E1_N; }
    if (e >= E) return;
    int p = atomicAdd(&hp[edp[e]], 1);
    sp[p] = esp[e];
}

// ---------------------------------------------------------------------------
// Per-node projections, mode-fused. 8 lanes/node, weight slices in regs.
// Writes COMPACT per-list tables (R1 layout -- 8B/4B stride, best measured
// FETCH locality; the 16B-stride float4 tables of R4/R6 cost +45MB FETCH):
//   pcor[s] = (p0_m0, p1_m0)  e-logits for cor list (walked by mode 0)
//   psim[s] = (p0_m1, p1_m1)  e-logits for sim list (walked by mode 1)
//   qsim[s] = q_m0            i-logit  for sim list (walked by mode 0)
//   qcor[s] = q_m1            i-logit  for cor list (walked by mode 1)
// dst-side components in pd/qd with ND0 mode stride.
// ---------------------------------------------------------------------------
#define NP_NPB 128
__global__ __launch_bounds__(256) void node_proj(
    const ushort* __restrict__ zb, size_t zstr,
    const float* __restrict__ Web, const float* __restrict__ Wib,
    float2* __restrict__ pcor, float2* __restrict__ psim,
    float* __restrict__ qcor, float* __restrict__ qsim,
    float* __restrict__ pdb, float* __restrict__ qdb,
    int n_src, int n_dst)
{
    const int m = blockIdx.y;
    const ushort* z = zb + m * zstr;
    const float* We = Web + m * 512;
    const float* Wi = Wib + m * 256;

    __shared__ float w[6][D_DIM];
    for (int k = threadIdx.x; k < D_DIM; k += 256) {
        w[0][k] = We[k * 2 + 0];
        w[1][k] = We[k * 2 + 1];
        w[2][k] = Wi[k];
        w[3][k] = We[(D_DIM + k) * 2 + 0];
        w[4][k] = We[(D_DIM + k) * 2 + 1];
        w[5][k] = Wi[D_DIM + k];
    }
    __syncthreads();

    const int sub = threadIdx.x & 7;
    const int g   = threadIdx.x >> 3;

    float wr[6][16];
    #pragma unroll
    for (int c = 0; c < 6; ++c)
        #pragma unroll
        for (int q = 0; q < 4; ++q) {
            float4 f = *(const float4*)(&w[c][sub * 16 + q * 4]);
            wr[c][q * 4 + 0] = f.x; wr[c][q * 4 + 1] = f.y;
            wr[c][q * 4 + 2] = f.z; wr[c][q * 4 + 3] = f.w;
        }

    #pragma unroll
    for (int it = 0; it < 4; ++it) {
        int node = blockIdx.x * NP_NPB + it * 32 + g;
        if (node >= n_src) continue;
        const ushort* zp = z + (size_t)node * D_DIM + sub * 16;
        uint4 ra = *(const uint4*)zp;
        uint4 rb = *(const uint4*)(zp + 8);
        uint rr[8] = {ra.x, ra.y, ra.z, ra.w, rb.x, rb.y, rb.z, rb.w};
        float p[6] = {0.f, 0.f, 0.f, 0.f, 0.f, 0.f};
        #pragma unroll
        for (int e = 0; e < 8; ++e) {
            float2 f2 = unpack2(rr[e]);
            #pragma unroll
            for (int c = 0; c < 6; ++c)
                p[c] += f2.x * wr[c][2 * e] + f2.y * wr[c][2 * e + 1];
        }
        #pragma unroll
        for (int off = 4; off > 0; off >>= 1)
            #pragma unroll
            for (int c = 0; c < 6; ++c)
                p[c] += __shfl_down(p[c], off);

        if (sub == 0) {
            if (m == 0) {
                pcor[node] = make_float2(p[0], p[1]);
                qsim[node] = p[2];
            } else {
                psim[node] = make_float2(p[0], p[1]);
                qcor[node] = p[2];
            }
            if (node < n_dst) {
                *(float2*)(pdb + (size_t)m * ND0 * 2 + 2 * (size_t)node) = make_float2(p[3], p[4]);
                qdb[(size_t)m * ND0 + node] = p[5];
            }
        }
    }
}

// ---------------------------------------------------------------------------
// FUSED edge attention + gather, per-(dst, mode) wave (blockIdx.y = mode).
// R1-measured-best structure AND table layout (82.9us @ 270MB FETCH):
// sequential e-loop then i-loop, chunked, single LDS scratch, compact
// 8B-stride float2 e-tables / 4B-stride float i-tables.
// ---------------------------------------------------------------------------
__global__ __launch_bounds__(256) void edge_gather5(
    const ushort* __restrict__ zb, size_t zstr,
    const float2* __restrict__ pcor, const float2* __restrict__ psim,
    const float* __restrict__ qcor, const float* __restrict__ qsim,
    const float* __restrict__ pdb, const float* __restrict__ qdb,
    const int* __restrict__ row_c, const int* __restrict__ src_c,
    const int* __restrict__ row_s, const int* __restrict__ src_s,
    ushort* __restrict__ h0base, float* __restrict__ partialb,
    float* __restrict__ cvecb, int n_dst)
{
    __shared__ uint2 sc[4][64];   // per-wave (weight, src) scratch

    const int m = blockIdx.y;
    const int wv = threadIdx.x >> 6;
    const int d = blockIdx.x * 4 + wv;
    const int lane = threadIdx.x & 63;
    if (d >= n_dst) return;

    const ushort* z = zb + (size_t)m * zstr;
    const ushort* zlane = z + lane * 2;

    const int* erow = m ? row_s : row_c;
    const int* esrc = m ? src_s : src_c;
    const int* irow = m ? row_c : row_s;
    const int* isrc = m ? src_c : src_s;
    const float2* etab = m ? psim : pcor;   // e-logits for mode m's e-list
    const float*  itab = m ? qcor : qsim;   // i-logit  for mode m's i-list

    const float pd0 = pdb[(size_t)m * ND0 * 2 + 2 * d];
    const float pd1 = pdb[(size_t)m * ND0 * 2 + 2 * d + 1];
    const float qdd = qdb[(size_t)m * ND0 + d];

    float h0x = 0.f, h0y = 0.f, szx = 0.f, szy = 0.f;
    float ihx = 0.f, ihy = 0.f;
    float se0 = 0.f;

    // ---- e-channel loop
    const int b0 = erow[d], b1 = erow[d + 1];
    for (int base = b0; base < b1; base += 64) {
        const int cnt = min(64, b1 - base);
        if (lane < cnt) {
            int s = esrc[base + lane];
            float2 t = etab[s];
            float l0 = t.x + pd0, l1 = t.y + pd1;
            float mx = fmaxf(l0, l1);
            float x0 = __expf(l0 - mx), x1 = __expf(l1 - mx);
            float e0 = x0 / (x0 + x1);
            sc[wv][lane] = make_uint2(f2u(e0), (uint)s);
            se0 += e0;
        }
        asm volatile("s_waitcnt lgkmcnt(0)" ::: "memory");
        const int kf = cnt & ~7;
        int k = 0;
        for (; k < kf; k += 8) {
            uint2 ew[8]; uint rr[8];
            #pragma unroll
            for (int t = 0; t < 8; ++t) ew[t] = sc[wv][k + t];
            #pragma unroll
            for (int t = 0; t < 8; ++t) rr[t] = *(const uint*)(zlane + (size_t)ew[t].y * D_DIM);
            #pragma unroll
            for (int t = 0; t < 8; ++t) {
                float w0 = u2f(ew[t].x);
                float2 v = unpack2(rr[t]);
                szx += v.x; szy += v.y;
                h0x += w0 * v.x; h0y += w0 * v.y;
            }
        }
        if (k < cnt) {   // predicated batch of 8
            uint2 ew[8]; uint rr[8];
            #pragma unroll
            for (int t = 0; t < 8; ++t) ew[t] = sc[wv][(k + t) & 63];
            #pragma unroll
            for (int t = 0; t < 8; ++t) {
                uint s = (k + t < cnt) ? ew[t].y : 0u;
                rr[t] = *(const uint*)(zlane + (size_t)s * D_DIM);
            }
            #pragma unroll
            for (int t = 0; t < 8; ++t) {
                float sel = (k + t < cnt) ? 1.0f : 0.0f;
                float w0 = u2f(ew[t].x) * sel;
                float2 v = unpack2(rr[t]);
                szx += v.x * sel; szy += v.y * sel;
                h0x += w0 * v.x; h0y += w0 * v.y;
            }
        }
    }

    // cvec = (sum e0) / deg
    #pragma unroll
    for (int off = 32; off > 0; off >>= 1)
        se0 += __shfl_down(se0, off);
    if (lane == 0)
        cvecb[(size_t)m * ND0 + d] = se0 / fmaxf((float)(b1 - b0), 1.0f);

    // ---- i-channel loop
    const int c0 = irow[d], c1 = irow[d + 1];
    for (int base = c0; base < c1; base += 64) {
        const int cnt = min(64, c1 - base);
        if (lane < cnt) {
            int s = isrc[base + lane];
            float ti = itab[s];
            float sg = 1.0f / (1.0f + __expf(-(ti + qdd)));
            sc[wv][lane] = make_uint2(f2u(sg), (uint)s);
        }
        asm volatile("s_waitcnt lgkmcnt(0)" ::: "memory");
        const int kf = cnt & ~7;
        int k = 0;
        for (; k < kf; k += 8) {
            uint2 ew[8]; uint rr[8];
            #pragma unroll
            for (int t = 0; t < 8; ++t) ew[t] = sc[wv][k + t];
            #pragma unroll
            for (int t = 0; t < 8; ++t) rr[t] = *(const uint*)(zlane + (size_t)ew[t].y * D_DIM);
            #pragma unroll
            for (int t = 0; t < 8; ++t) {
                float g = u2f(ew[t].x);
                float2 v = unpack2(rr[t]);
                ihx += g * v.x; ihy += g * v.y;
            }
        }
        if (k < cnt) {
            uint2 ew[8]; uint rr[8];
            #pragma unroll
            for (int t = 0; t < 8; ++t) ew[t] = sc[wv][(k + t) & 63];
            #pragma unroll
            for (int t = 0; t < 8; ++t) {
                uint s = (k + t < cnt) ? ew[t].y : 0u;
                rr[t] = *(const uint*)(zlane + (size_t)s * D_DIM);
            }
            #pragma unroll
            for (int t = 0; t < 8; ++t) {
                float sel = (k + t < cnt) ? 1.0f : 0.0f;
                float g = u2f(ew[t].x) * sel;
                float2 v = unpack2(rr[t]);
                ihx += g * v.x; ihy += g * v.y;
            }
        }
    }

    // ---- epilogue
    const int nE = b1 - b0;
    float ehx = szx - h0x, ehy = szy - h0y;   // e1 = 1 - e0
    float inv = 1.0f / fmaxf((float)nE, 1.0f);
    uint hp = (uint)f2bf(h0x * inv) | ((uint)f2bf(h0y * inv) << 16);
    const size_t MSTR = (size_t)ND0 * D_DIM;
    *(uint*)(h0base + (size_t)m * MSTR + (size_t)d * D_DIM + lane * 2) = hp;

    float2 zd = unpack2(*(const uint*)(zlane + (size_t)d * D_DIM));
    float px = 0.5f * (fmaxf(ehx * ihx, 0.f) + zd.x);
    float py = 0.5f * (fmaxf(ehy * ihy, 0.f) + zd.y);
    *(float2*)(partialb + (size_t)m * MSTR + (size_t)d * D_DIM + lane * 2) =
        make_float2(px, py);
}

// ---------------------------------------------------------------------------
extern "C" void kernel_launch(void* const* d_in, const int* in_sizes, int n_in,
                              void* d_out, int out_size, void* d_ws, size_t ws_size,
                              hipStream_t stream)
{
    const float* feat = (const float*)d_in[0];
    const int* src0_cor = (const int*)d_in[1];
    const int* dst0_cor = (const int*)d_in[2];
    const int* src0_sim = (const int*)d_in[3];
    const int* dst0_sim = (const int*)d_in[4];
    const int* src1_cor = (const int*)d_in[5];
    const int* dst1_cor = (const int*)d_in[6];
    const int* src1_sim = (const int*)d_in[7];
    const int* dst1_sim = (const int*)d_in[8];
    const float* Win  = (const float*)d_in[11];
    const float* b_in = (const float*)d_in[12];
    const float* ea1  = (const float*)d_in[14];
    const float* ia1  = (const float*)d_in[15];
    const float* W1   = (const float*)d_in[16];
    const float* b1   = (const float*)d_in[17];
    const float* ea2  = (const float*)d_in[19];
    const float* ia2  = (const float*)d_in[20];
    const float* W2   = (const float*)d_in[21];
    const float* b2   = (const float*)d_in[22];
    const float* Wout = (const float*)d_in[23];
    const float* bout = (const float*)d_in[24];
    (void)in_sizes; (void)n_in; (void)out_size; (void)ws_size;

    // ---- workspace layout ----
    char* wsb = (char*)d_ws;
    size_t off = 0;
    auto alloc_f  = [&](size_t n) { float*  p = (float*) (wsb + off); off += n * 4; return p; };
    auto alloc_f2 = [&](size_t n) { float2* p = (float2*)(wsb + off); off += n * 8; return p; };
    auto alloc_i  = [&](size_t n) { int*    p = (int*)   (wsb + off); off += n * 4; return p; };
    auto alloc_h  = [&](size_t n) { ushort* p = (ushort*)(wsb + off); off += ((n * 2 + 15) & ~15ull); return p; };

    ushort* z0b   = alloc_h((size_t)2 * NS0 * D_DIM);
    ushort* z1b   = alloc_h((size_t)2 * NS1 * D_DIM);
    ushort* z2b   = alloc_h((size_t)2 * ND1 * D_DIM);
    ushort* h0b   = alloc_h((size_t)2 * ND0 * D_DIM);
    ushort* Wtin  = alloc_h((size_t)2 * D_DIM * F_DIM);
    ushort* Wt1   = alloc_h((size_t)2 * D_DIM * D_DIM);
    ushort* Wt2   = alloc_h((size_t)2 * D_DIM * D_DIM);
    ushort* Wtout = alloc_h((size_t)2 * O_DIM * D_DIM);

    float2* pcor   = alloc_f2((size_t)NS0);
    float2* psim   = alloc_f2((size_t)NS0);
    float* qcor    = alloc_f((size_t)NS0);
    float* qsim    = alloc_f((size_t)NS0);
    float* pd      = alloc_f((size_t)2 * ND0 * 2);
    float* qd      = alloc_f((size_t)2 * ND0);
    float* cvec    = alloc_f((size_t)2 * ND0);
    float* partial = alloc_f((size_t)2 * ND0 * D_DIM);

    int* src_c0 = alloc_i(E0_N); int* row_c0 = alloc_i(ND0 + 1);
    int* src_s0 = alloc_i(E0_N); int* row_s0 = alloc_i(ND0 + 1);
    int* src_c1 = alloc_i(E1_N); int* row_c1 = alloc_i(ND1 + 1);
    int* src_s1 = alloc_i(E1_N); int* row_s1 = alloc_i(ND1 + 1);
    int* cnt_all  = alloc_i(2 * ND0 + 2 * ND1);
    int* head_all = alloc_i(2 * ND0 + 2 * ND1);

    int* cnt_c0 = cnt_all;            int* head_c0 = head_all;
    int* cnt_s0 = cnt_all + ND0;      int* head_s0 = head_all + ND0;
    int* cnt_c1 = cnt_all + 2 * ND0;  int* head_c1 = head_all + 2 * ND0;
    int* cnt_s1 = cnt_c1 + ND1;       int* head_s1 = head_c1 + ND1;

    // ---- batched CSR build + weight prep ----
    hipMemsetAsync(cnt_all, 0, (size_t)(2 * ND0 + 2 * ND1) * 4, stream);
    {
        CPtr4 edp  = {dst0_cor, dst0_sim, dst1_cor, dst1_sim};
        CPtr4 esp  = {src0_cor, src0_sim, src1_cor, src1_sim};
        MPtr4 cntp = {cnt_c0, cnt_s0, cnt_c1, cnt_s1};
        MPtr4 rowp = {row_c0, row_s0, row_c1, row_s1};
        MPtr4 hdp  = {head_c0, head_s0, head_c1, head_s1};
        MPtr4 srcp = {src_c0, src_s0, src_c1, src_s1};
        histo4_prep<<<NB_CSR + NB_WPREP, 256, 0, stream>>>(
            edp, cntp, Win, W1, W2, Wout, Wtin, Wt1, Wt2, Wtout);
        exscan4<<<4, 1024, 0, stream>>>(cntp, rowp, hdp);
        build4<<<NB_CSR, 256, 0, stream>>>(esp, edp, hdp, srcp);
    }

    // ======== both modes fused ========
    const size_t Z0S = (size_t)NS0 * D_DIM, Z1S = (size_t)NS1 * D_DIM;
    const size_t Z2S = (size_t)ND1 * D_DIM, H0S = (size_t)ND0 * D_DIM;

    // --- Layer 0: z0[m] = feat @ Win[m] + b_in[m]  (A staged once for both modes)
    gemm_l0<<<(NS0 + 63) / 64, 256, 0, stream>>>(
        feat, Wtin, b_in, z0b, Z0S, NS0);

    // --- Layer 1
    node_proj<<<dim3((NS0 + NP_NPB - 1) / NP_NPB, 2), 256, 0, stream>>>(
        z0b, Z0S, ea1, ia1, pcor, psim, qcor, qsim, pd, qd, NS0, ND0);
    edge_gather5<<<dim3((ND0 + 3) / 4, 2), 256, 0, stream>>>(
        z0b, Z0S, pcor, psim, qcor, qsim, pd, qd,
        row_c0, src_c0, row_s0, src_s0, h0b, partial, cvec, ND0);
    mfma_gemm<128, 128, 2><<<dim3((ND0 + 127) / 128, 2), 256, 0, stream>>>(
        h0b, H0S, Wt1, (size_t)D_DIM * D_DIM, b1, D_DIM,
        cvec, ND0, partial, H0S, z1b, Z1S, ND0);

    // --- Layer 2
    node_proj<<<dim3((NS1 + NP_NPB - 1) / NP_NPB, 2), 256, 0, stream>>>(
        z1b, Z1S, ea2, ia2, pcor, psim, qcor, qsim, pd, qd, NS1, ND1);
    edge_gather5<<<dim3((ND1 + 3) / 4, 2), 256, 0, stream>>>(
        z1b, Z1S, pcor, psim, qcor, qsim, pd, qd,
        row_c1, src_c1, row_s1, src_s1, h0b, partial, cvec, ND1);
    mfma_gemm<128, 128, 2><<<dim3((ND1 + 127) / 128, 2), 256, 0, stream>>>(
        h0b, H0S, Wt2, (size_t)D_DIM * D_DIM, b2, D_DIM,
        cvec, ND0, partial, H0S, z2b, Z2S, ND1);

    // --- Output: out[m] = z2 @ Wout[m] + bout[m]  (fp32 out)
    mfma_gemm<64, 128, 1><<<dim3((ND1 + 127) / 128, 2), 256, 0, stream>>>(
        z2b, Z2S, Wtout, (size_t)O_DIM * D_DIM, bout, O_DIM,
        nullptr, 0, nullptr, 0, (float*)d_out, (size_t)ND1 * O_DIM, ND1);
}